// Round 19
// baseline (165.383 us; speedup 1.0000x reference)
//
#include <hip/hip_runtime.h>

// ---------------------------------------------------------------------------
// DPM_Block — Round 19: 512-thread conv+vg blocks (8 waves share the 64KB
// B-tile: occupancy 8->16 waves/CU, staging halved); k_scores bounds (256,4).
// Rest identical to R18 (141.2us).
// ---------------------------------------------------------------------------

#define Bn 128
#define Sn 49
#define Cn 512
#define Ln 1000
#define BL (Bn*Ln)
#define VQ 2048

typedef unsigned short u16;
typedef unsigned int u32;

using bfrag = __attribute__((ext_vector_type(8))) short;   // 8 bf16 (4 VGPR)
using ffrag = __attribute__((ext_vector_type(4))) float;   // 4 f32 acc

typedef const __attribute__((address_space(1))) u32 gq_t;
typedef __attribute__((address_space(3))) u32 lq_t;

__device__ __forceinline__ float bf2f(u16 u){ return __uint_as_float(((u32)u) << 16); }
__device__ __forceinline__ float bflo(u32 u){ return __uint_as_float(u << 16); }
__device__ __forceinline__ float bfhi(u32 u){ return __uint_as_float(u & 0xffff0000u); }
__device__ __forceinline__ u16 f2bf(float f){
  u32 x = __float_as_uint(f);
  u32 r = x + 0x7fffu + ((x >> 16) & 1u);   // RNE
  return (u16)(r >> 16);
}
__device__ __forceinline__ u16 f2h(float f){
  _Float16 h = (_Float16)f; return *(u16*)&h;
}
__device__ __forceinline__ float h2f(u16 u){
  _Float16 h = *(_Float16*)&u; return (float)h;
}

template<int BF>
__device__ __forceinline__ float ldin(const void* p, int i){
  if (BF) return bf2f(((const u16*)p)[i]);
  return ((const float*)p)[i];
}

template<int BF>
__device__ __forceinline__ void ld8(const void* p, int base, float* w){
  if (BF){
    uint4 u = *(const uint4*)((const u16*)p + base);
    w[0]=bflo(u.x); w[1]=bfhi(u.x); w[2]=bflo(u.y); w[3]=bfhi(u.y);
    w[4]=bflo(u.z); w[5]=bfhi(u.z); w[6]=bflo(u.w); w[7]=bfhi(u.w);
  } else {
    float4 a = *(const float4*)((const float*)p + base);
    float4 b = *(const float4*)((const float*)p + base + 4);
    w[0]=a.x; w[1]=a.y; w[2]=a.z; w[3]=a.w;
    w[4]=b.x; w[5]=b.y; w[6]=b.z; w[7]=b.w;
  }
}

__device__ __forceinline__ uint4 pack8(const float* w){
  uint4 v;
  v.x = (u32)f2bf(w[0]) | ((u32)f2bf(w[1])<<16);
  v.y = (u32)f2bf(w[2]) | ((u32)f2bf(w[3])<<16);
  v.z = (u32)f2bf(w[4]) | ((u32)f2bf(w[5])<<16);
  v.w = (u32)f2bf(w[6]) | ((u32)f2bf(w[7])<<16);
  return v;
}

__device__ __forceinline__ float ld_gamma(const void* p, int BF){
  float fb = bf2f(((const u16*)p)[0]);
  float ff = ((const float*)p)[0];
  bool pb = (fb > 0.05f && fb < 1.5f);
  bool pf = (ff > 0.05f && ff < 1.5f);
  if (pb && !pf) return fb;
  if (pf && !pb) return ff;
  return BF ? fb : ff;
}

// ---- inline dtype detector ----
__device__ __forceinline__ int detect_bf(const void* Fs){
  int lane = threadIdx.x & 63;
  uint4 v = ((const uint4*)Fs)[lane];
  u32 w[4] = {v.x, v.y, v.z, v.w};
  int c = 0;
  #pragma unroll
  for (int j = 0; j < 4; ++j){
    int e = (w[j] >> 7) & 0xff;
    c += (e >= 0x70 && e <= 0x8f);
  }
  #pragma unroll
  for (int m = 32; m; m >>= 1) c += __shfl_xor(c, m);
  return c >= 200;
}

// 256-thread block reduction (scratch 8 floats x2)
__device__ __forceinline__ float2 block_red2(float a, float b, float* scratch){
  __syncthreads();
  #pragma unroll
  for (int off = 32; off; off >>= 1){ a += __shfl_xor(a, off); b += __shfl_xor(b, off); }
  int lane = threadIdx.x & 63, wid = threadIdx.x >> 6;
  if (lane == 0){ scratch[wid] = a; scratch[wid + 4] = b; }
  __syncthreads();
  return make_float2(scratch[0] + scratch[1] + scratch[2] + scratch[3],
                     scratch[4] + scratch[5] + scratch[6] + scratch[7]);
}

// 512-thread block reduction (scratch 16 floats)
__device__ __forceinline__ float2 block_red2_512(float a, float b, float* scratch){
  __syncthreads();
  #pragma unroll
  for (int off = 32; off; off >>= 1){ a += __shfl_xor(a, off); b += __shfl_xor(b, off); }
  int lane = threadIdx.x & 63, wid = threadIdx.x >> 6;
  if (lane == 0){ scratch[wid] = a; scratch[wid + 8] = b; }
  __syncthreads();
  float ra = 0.f, rb = 0.f;
  #pragma unroll
  for (int i = 0; i < 8; ++i){ ra += scratch[i]; rb += scratch[i + 8]; }
  return make_float2(ra, rb);
}

// -------------------- bodies --------------------
template<int BF>
__device__ void gn1_body(int b, const void* Fs, float* m1, float* rs1, u16* Fsb,
                         float* m2s, float* m2ss, float* red){
  int tid = threadIdx.x;
  if (tid == 0){ m2s[b] = 0.f; m2ss[b] = 0.f; }
  float s = 0.f, ss = 0.f;
  for (int i = tid; i < Sn*Cn/8; i += 256){
    float w[8]; ld8<BF>(Fs, b*Sn*Cn + i*8, w);
    #pragma unroll
    for (int j = 0; j < 8; ++j){ s += w[j]; ss += w[j]*w[j]; }
    *(uint4*)(Fsb + (size_t)b*Sn*Cn + i*8) = pack8(w);
  }
  float2 r = block_red2(s, ss, red);
  if (tid == 0){
    float m = r.x * (1.f/(Sn*Cn));
    float v = r.y * (1.f/(Sn*Cn)) - m*m;
    m1[b] = m; rs1[b] = rsqrtf(v + 1e-5f);
  }
}

template<int BF>
__device__ void wk_body(int blk, const void* W1, const void* W2, const void* W3,
    const void* W4, const void* g1, const void* g2, const void* bb1, const void* bb2,
    const void* bias1, const void* bias2,
    u16* D1, u16* D2, u16* D3, u16* D4,
    float* K1a, float* K1b, float* K2a, float* K2b){
  if (blk < 512){
    int i = blk*256 + threadIdx.x;
    int sel = i >> 15;
    const void* src = (sel==0) ? W1 : (sel==1) ? W2 : (sel==2) ? W3 : W4;
    u16* dst = (sel==0) ? D1 : (sel==1) ? D2 : (sel==2) ? D3 : D4;
    int off = (i & 32767)*8;
    float w[8]; ld8<BF>(src, off, w);
    if (sel <= 1){
      const void* g = sel ? g2 : g1;
      int c0 = off & 511;
      #pragma unroll
      for (int j = 0; j < 8; ++j) w[j] *= ldin<BF>(g, c0 + j);
    }
    *(uint4*)(dst + off) = pack8(w);
  } else {
    int idx = (blk - 512)*4 + (threadIdx.x >> 6);
    int lane = threadIdx.x & 63;
    int o = idx & 511, sel = idx >> 9;
    const void* W  = sel ? W2 : W1;
    const void* g  = sel ? g2 : g1;
    const void* bb = sel ? bb2 : bb1;
    const void* bi = sel ? bias2 : bias1;
    float* Ka = sel ? K2a : K1a;
    float* Kb = sel ? K2b : K1b;
    float w[8], gv[8], bv[8];
    ld8<BF>(W, o*Cn + lane*8, w);
    ld8<BF>(g, lane*8, gv);
    ld8<BF>(bb, lane*8, bv);
    float a = 0.f, b2 = 0.f;
    #pragma unroll
    for (int j = 0; j < 8; ++j){ a += w[j]*bv[j]; b2 += w[j]*gv[j]; }
    #pragma unroll
    for (int m = 32; m; m >>= 1){ a += __shfl_xor(a, m); b2 += __shfl_xor(b2, m); }
    if (lane == 0){ Ka[o] = a + ldin<BF>(bi, o); Kb[o] = b2; }
  }
}

template<int BF>
__device__ void protonorm_body(int l, const void* Ft, const void* Pr,
                               float* invFt, float* invPr,
                               u16* FtB, u16* PrB, float* red){
  int tid = threadIdx.x;
  if (l >= Ln){
    FtB[(size_t)l*512 + tid] = 0; FtB[(size_t)l*512 + tid + 256] = 0;
    PrB[(size_t)l*512 + tid] = 0; PrB[(size_t)l*512 + tid + 256] = 0;
    return;
  }
  float a0 = ldin<BF>(Ft, l*Cn + tid), a1 = ldin<BF>(Ft, l*Cn + tid + 256);
  float p0 = ldin<BF>(Pr, l*Cn + tid), p1 = ldin<BF>(Pr, l*Cn + tid + 256);
  FtB[(size_t)l*512 + tid] = f2bf(a0); FtB[(size_t)l*512 + tid + 256] = f2bf(a1);
  PrB[(size_t)l*512 + tid] = f2bf(p0); PrB[(size_t)l*512 + tid + 256] = f2bf(p1);
  float2 r = block_red2(a0*a0 + a1*a1, p0*p0 + p1*p1, red);
  if (tid == 0){
    invFt[l] = 1.f / fmaxf(sqrtf(r.x), 1e-12f);
    invPr[l] = 1.f / fmaxf(sqrtf(r.y), 1e-12f);
  }
}

// ---- launch 1: [0,512) wconv, [512,768) kvec, [768,1792) protonorm,
//      [1792,1920) gn1 ----
__global__ __launch_bounds__(256) void k_gn1wk(const void* Fs,
    const void* W1, const void* W2, const void* W3, const void* W4,
    const void* g1, const void* g2, const void* bb1, const void* bb2,
    const void* bias1, const void* bias2,
    u16* D1, u16* D2, u16* D3, u16* D4,
    float* K1a, float* K1b, float* K2a, float* K2b,
    const void* Ft, const void* Pr, float* invFt, float* invPr, u16* FtB, u16* PrB,
    float* m1, float* rs1, u16* Fsb, float* m2s, float* m2ss){
  __shared__ float red[8];
  int bf = detect_bf(Fs);
  int blk = blockIdx.x;
  if (blk < 768){
    if (bf) wk_body<1>(blk, W1, W2, W3, W4, g1, g2, bb1, bb2, bias1, bias2,
                       D1, D2, D3, D4, K1a, K1b, K2a, K2b);
    else    wk_body<0>(blk, W1, W2, W3, W4, g1, g2, bb1, bb2, bias1, bias2,
                       D1, D2, D3, D4, K1a, K1b, K2a, K2b);
  } else if (blk < 1792){
    int l = blk - 768;
    if (bf) protonorm_body<1>(l, Ft, Pr, invFt, invPr, FtB, PrB, red);
    else    protonorm_body<0>(l, Ft, Pr, invFt, invPr, FtB, PrB, red);
  } else {
    int b = blk - 1792;
    if (bf) gn1_body<1>(b, Fs, m1, rs1, Fsb, m2s, m2ss, red);
    else    gn1_body<0>(b, Fs, m1, rs1, Fsb, m2s, m2ss, red);
  }
}

// ------- MFMA conv body, 512 threads (8 waves share one B-tile) -------------
template<int C1>
__device__ void convm_body(int b, int o0,
    const u16* __restrict__ src, const u16* __restrict__ Wb,
    const float* __restrict__ Ka, const float* __restrict__ Kb,
    float mean, float rs, u16* dst, u16* Bs, float* red,
    float* m2s, float* m2ss){
  int tid = threadIdx.x;
  int lane = tid & 63, wid = tid >> 6, lq = lane & 15, g4 = lane >> 4;
  for (int idx = tid; idx < 15*64; idx += 512){
    int r = 49 + (idx >> 6), j = idx & 63;
    *(uint4*)(Bs + (r<<9) + (j<<3)) = (uint4){0,0,0,0};
  }
  #pragma unroll
  for (int is = 0; is < 7; ++is){
    int r = is*8 + wid;
    if (r < Sn){
      const u16* gsrc = src + (size_t)(b*Sn + r)*Cn + ((lane ^ (r & 7)) << 3);
      u16* ldst = Bs + (r << 9);
      __builtin_amdgcn_global_load_lds((gq_t*)gsrc, (lq_t*)ldst, 16, 0, 0);
    }
  }
  __syncthreads();
  float gs = 0.f, gss = 0.f;
  #pragma unroll
  for (int ot = 0; ot < 2; ++ot){
    int oA = o0 + wid*32 + ot*16;
    bfrag af[16];
    #pragma unroll
    for (int kb = 0; kb < 16; ++kb)
      af[kb] = *(const bfrag*)(Wb + (size_t)(oA + lq)*Cn + kb*32 + g4*8);
    ffrag acc[4];
    #pragma unroll
    for (int st = 0; st < 4; ++st) acc[st] = (ffrag){0.f,0.f,0.f,0.f};
    #pragma unroll
    for (int st = 0; st < 4; ++st){
      int srow = st*16 + lq;
      #pragma unroll
      for (int kb = 0; kb < 16; ++kb){
        bfrag bf_ = *(const bfrag*)(Bs + (srow<<9) + (((kb*4+g4) ^ (srow&7))<<3));
        acc[st] = __builtin_amdgcn_mfma_f32_16x16x32_bf16(af[kb], bf_, acc[st], 0,0,0);
      }
    }
    int ob = oA + g4*4;
    float cst[4];
    #pragma unroll
    for (int r = 0; r < 4; ++r) cst[r] = Ka[ob + r] - mean*rs*Kb[ob + r];
    #pragma unroll
    for (int st = 0; st < 4; ++st){
      int s = st*16 + lq;
      u16 pk[4];
      #pragma unroll
      for (int r = 0; r < 4; ++r){
        float val = rs*acc[st][r] + cst[r];
        if (C1){
          val = fmaxf(val, 0.f);
          if (s < Sn){ gs += val; gss += val*val; }
        }
        pk[r] = f2bf(val);
      }
      if (C1){
        if (s < Sn) *(uint2*)(dst + ((size_t)(b*Sn + s)<<9) + ob) = *(const uint2*)pk;
      } else {
        if (s >= Sn){ pk[0]=0; pk[1]=0; pk[2]=0; pk[3]=0; }
        *(uint2*)(dst + ((size_t)(b*64 + s)<<9) + ob) = *(const uint2*)pk;
      }
    }
  }
  if (C1){
    float2 r2 = block_red2_512(gs, gss, red);
    if (tid == 0){
      atomicAdd(&m2s[b], r2.x);
      atomicAdd(&m2ss[b], r2.y);
    }
  }
}

// ------------- vector MLP body, 512 threads (8 waves, 1 tile each) ----------
template<int BF, int SBF, int PH>
__device__ void vg_body(int o0, const void* src, const void* lng, const void* lnb,
    const u16* __restrict__ Wv, const void* bias, void* outp,
    u16* Bt, u16* Ach, float* mrow, float* rrow, float* Gc, float* Bc2){
  int tid = threadIdx.x, lane = tid & 63, wid = tid >> 6;
  int lq = lane & 15, g4 = lane >> 4;
  for (int c = tid; c < Cn; c += 512){ Gc[c] = ldin<BF>(lng, c); Bc2[c] = ldin<BF>(lnb, c); }
  {
    int r = tid >> 2, h = tid & 3;
    float s = 0.f, ss = 0.f;
    #pragma unroll 4
    for (int k = 0; k < 16; ++k){
      float w[8]; ld8<SBF>(src, r*Cn + h*128 + k*8, w);
      #pragma unroll
      for (int j = 0; j < 8; ++j){ s += w[j]; ss += w[j]*w[j]; }
    }
    s += __shfl_xor(s, 1); ss += __shfl_xor(ss, 1);
    s += __shfl_xor(s, 2); ss += __shfl_xor(ss, 2);
    if (h == 0){
      float m = s * (1.f/Cn);
      mrow[r] = m; rrow[r] = rsqrtf(ss * (1.f/Cn) - m*m + 1e-5f);
    }
  }
  for (int idx = tid; idx < 16*64; idx += 512){
    int row = idx >> 6, j = idx & 63;
    uint4 v = *(const uint4*)(Wv + (size_t)(o0 + row)*Cn + j*8);
    *(uint4*)(Bt + (row<<9) + ((j ^ (row&7))<<3)) = v;
  }
  __syncthreads();
  ffrag acc = (ffrag){0.f,0.f,0.f,0.f};
  for (int kc = 0; kc < 4; ++kc){
    if (kc) __syncthreads();
    for (int idx = tid; idx < 128*16; idx += 512){
      int row = idx >> 4, j = idx & 15;
      int c = kc*128 + j*8;
      float w[8]; ld8<SBF>(src, row*Cn + c, w);
      float mu = mrow[row], rsd = rrow[row];
      #pragma unroll
      for (int k2 = 0; k2 < 8; ++k2) w[k2] = (w[k2]-mu)*rsd*Gc[c+k2] + Bc2[c+k2];
      *(uint4*)(Ach + (row<<7) + ((j ^ (row&15))<<3)) = pack8(w);
    }
    __syncthreads();
    int arow = wid*16 + lq;
    #pragma unroll
    for (int kb = 0; kb < 4; ++kb){
      bfrag af = *(const bfrag*)(Ach + (arow<<7) + (((kb*4+g4) ^ (arow&15))<<3));
      bfrag bf_ = *(const bfrag*)(Bt + (lq<<9) + (((kc*16 + kb*4 + g4) ^ (lq&7))<<3));
      acc = __builtin_amdgcn_mfma_f32_16x16x32_bf16(af, bf_, acc, 0,0,0);
    }
  }
  float bval = ldin<BF>(bias, o0 + lq);
  #pragma unroll
  for (int r = 0; r < 4; ++r){
    int brow = wid*16 + g4*4 + r;
    float val = acc[r] + bval;
    if (PH == 1){
      ((u16*)outp)[brow*Cn + o0 + lq] = f2bf(fmaxf(val, 0.f));
    } else {
      ((float*)outp)[brow*Cn + o0 + lq] = val;
    }
  }
}

// LDS union: conv = 64KB Bs + 64B red; vg = 53KB carved
#define CV_SHARED __shared__ __align__(16) char smu[65600];

// ---- launch 2: vg1 (blocks 0..31) + conv1m (32..287, 2 o-slices/b) ----
__global__ __launch_bounds__(512, 4) void k_c1vg1(const void* Fs,
    const u16* Fsb, const u16* W1b, const float* Ka, const float* Kb,
    const float* m1, const float* rs1, u16* H1t, float* m2s, float* m2ss,
    const void* Fv, const void* ln1g, const void* ln1b,
    const u16* W1vb, const void* l1b, u16* Hb){
  CV_SHARED
  int blk = blockIdx.x;
  if (blk >= 32){
    u16* Bs = (u16*)smu;
    float* red = (float*)(smu + 65536);
    int cb = blk - 32;
    int b = cb >> 1, o0 = (cb & 1)*256;
    convm_body<1>(b, o0, Fsb, W1b, Ka, Kb, m1[b], rs1[b], H1t, Bs, red, m2s, m2ss);
  } else {
    u16* Bt = (u16*)smu;
    u16* Ach = (u16*)(smu + 16384);
    float* mrow = (float*)(smu + 49152);
    float* rrow = (float*)(smu + 49664);
    float* Gc = (float*)(smu + 50176);
    float* Bc2 = (float*)(smu + 52224);
    int o0 = blk*16;
    if (detect_bf(Fs)) vg_body<1,1,1>(o0, Fv, ln1g, ln1b, W1vb, l1b, Hb, Bt, Ach, mrow, rrow, Gc, Bc2);
    else               vg_body<0,0,1>(o0, Fv, ln1g, ln1b, W1vb, l1b, Hb, Bt, Ach, mrow, rrow, Gc, Bc2);
  }
}

// ---- launch 3: vg2 (blocks 0..31) + conv2m (32..287) ----
__global__ __launch_bounds__(512, 4) void k_c2vg2(const void* Fs,
    const u16* H1t, const u16* W2b, const float* Ka, const float* Kb,
    const float* m2s, const float* m2ss, u16* FspAug,
    const u16* Hb, const void* ln2g, const void* ln2b,
    const u16* W2vb, const void* l2b, float* Y2){
  CV_SHARED
  int blk = blockIdx.x;
  if (blk >= 32){
    u16* Bs = (u16*)smu;
    int cb = blk - 32;
    int b = cb >> 1, o0 = (cb & 1)*256;
    float sum = m2s[b], ssum = m2ss[b];
    float mean = sum * (1.f/(Sn*Cn));
    float var  = ssum * (1.f/(Sn*Cn)) - mean*mean;
    float rs = rsqrtf(var + 1e-5f);
    convm_body<0>(b, o0, H1t, W2b, Ka, Kb, mean, rs, FspAug, Bs,
                  (float*)nullptr, (float*)nullptr, (float*)nullptr);
  } else {
    u16* Bt = (u16*)smu;
    u16* Ach = (u16*)(smu + 16384);
    float* mrow = (float*)(smu + 49152);
    float* rrow = (float*)(smu + 49664);
    float* Gc = (float*)(smu + 50176);
    float* Bc2 = (float*)(smu + 52224);
    int o0 = blk*16;
    if (detect_bf(Fs)) vg_body<1,1,2>(o0, Hb, ln2g, ln2b, W2vb, l2b, Y2, Bt, Ach, mrow, rrow, Gc, Bc2);
    else               vg_body<0,1,2>(o0, Hb, ln2g, ln2b, W2vb, l2b, Y2, Bt, Ach, mrow, rrow, Gc, Bc2);
  }
}

// --- k_prep: Fvn = l2norm(Fvp) (fused); aug rows 56/57; G = Aug·Aug^T -------
__global__ __launch_bounds__(256) void k_prep(const float* __restrict__ Fvp,
    float* __restrict__ Fvn, u16* __restrict__ FspAug, u16* __restrict__ Gb){
  __shared__ u16 xa[64*512];
  __shared__ float red[8];
  __shared__ float fvrow[512];
  int b = blockIdx.x, tid = threadIdx.x;
  int lane = tid & 63, wid = tid >> 6, lq = lane & 15, g4 = lane >> 4;
  float x0 = Fvp[b*Cn + tid], x1 = Fvp[b*Cn + tid + 256];
  float2 rr = block_red2(x0*x0 + x1*x1, 0.f, red);
  float inv = 1.f / fmaxf(sqrtf(rr.x), 1e-12f);
  fvrow[tid] = x0*inv; fvrow[tid + 256] = x1*inv;
  Fvn[b*Cn + tid] = x0*inv; Fvn[b*Cn + tid + 256] = x1*inv;
  __syncthreads();
  for (int idx = tid; idx < 64*64; idx += 256){
    int s = idx >> 6, j = idx & 63;
    uint4 v;
    if (s == 56 || s == 57){
      float w[8];
      if (s == 56){
        const float* src = Fvp + b*Cn + j*8;
        #pragma unroll
        for (int k = 0; k < 8; ++k) w[k] = src[k];
      } else {
        #pragma unroll
        for (int k = 0; k < 8; ++k) w[k] = fvrow[j*8 + k];
      }
      v = pack8(w);
      *(uint4*)(FspAug + ((size_t)(b*64 + s))*512 + j*8) = v;
    } else {
      v = *(const uint4*)(FspAug + ((size_t)(b*64 + s))*512 + j*8);
    }
    *(uint4*)(xa + s*512 + ((j ^ (s&7)) << 3)) = v;
  }
  __syncthreads();
  int mt = wid;
  for (int nt = 0; nt < 4; ++nt){
    ffrag acc = {0.f, 0.f, 0.f, 0.f};
    #pragma unroll
    for (int kb = 0; kb < 16; ++kb){
      int j = kb*4 + g4;
      int rowa = mt*16 + lq, rowb = nt*16 + lq;
      bfrag af  = *(const bfrag*)(xa + rowa*512 + ((j ^ (rowa&7)) << 3));
      bfrag bf_ = *(const bfrag*)(xa + rowb*512 + ((j ^ (rowb&7)) << 3));
      acc = __builtin_amdgcn_mfma_f32_16x16x32_bf16(af, bf_, acc, 0, 0, 0);
    }
    #pragma unroll
    for (int r = 0; r < 4; ++r)
      Gb[(size_t)b*4096 + (mt*16 + g4*4 + r)*64 + nt*16 + lq] = f2bf(acc[r]);
  }
}

// ------- K1: scores GEMM -> f16; async staging; grid (Bn, 8) ---------------
__global__ __launch_bounds__(256, 4) void k_scores(const u16* __restrict__ LB,
    const u16* __restrict__ FspAug, u16* __restrict__ Sc){
  __shared__ u16 At[64*256];   // 32768 B
  int b = blockIdx.x, lg = blockIdx.y;
  int tid = threadIdx.x, lane = tid & 63, wid = tid >> 6;
  int lq = lane & 15, g4 = lane >> 4;
  int l32 = lane & 31, rh = lane >> 5;
  bfrag breg[16];
  {
    const u16* fa = FspAug + ((size_t)(b*64 + wid*16 + lq))*512 + g4*8;
    #pragma unroll
    for (int kb = 0; kb < 16; ++kb) breg[kb] = *(const bfrag*)(fa + kb*32);
  }
  for (int chunk = 0; chunk < 4; ++chunk){
    int qi = lg*4 + chunk;
    ffrag acc[4];
    #pragma unroll
    for (int lt = 0; lt < 4; ++lt) acc[lt] = (ffrag){0.f,0.f,0.f,0.f};
    for (int kc = 0; kc < 2; ++kc){
      __syncthreads();   // guard At rewrite
      #pragma unroll
      for (int is = 0; is < 8; ++is){
        int r = (is*4 + wid)*2 + rh;
        const u16* gsrc = LB + (size_t)(qi*64 + r)*512 + kc*256 + ((l32 ^ (r & 7)) << 3);
        u16* ldst = At + ((is*4 + wid) << 9);
        __builtin_amdgcn_global_load_lds((gq_t*)gsrc, (lq_t*)ldst, 16, 0, 0);
      }
      __syncthreads();
      #pragma unroll
      for (int kb = 0; kb < 8; ++kb){
        #pragma unroll
        for (int lt = 0; lt < 4; ++lt){
          int row = lt*16 + lq;
          bfrag af = *(const bfrag*)(At + (row<<8) + (((kb*4+g4) ^ (row&7))<<3));
          acc[lt] = __builtin_amdgcn_mfma_f32_16x16x32_bf16(af, breg[kc*8+kb], acc[lt], 0,0,0);
        }
      }
    }
    #pragma unroll
    for (int lt = 0; lt < 4; ++lt){
      #pragma unroll
      for (int r = 0; r < 4; ++r){
        size_t row = (size_t)b*VQ + qi*64 + lt*16 + g4*4 + r;
        Sc[row*64 + wid*16 + lq] = f2h(acc[lt][r]);
      }
    }
  }
}

// -- K2: row-per-lane softmax + gram epilogue; blocks >= 4096 do proto update
__global__ __launch_bounds__(64) void k_attn4(const void* Fs,
    const u16* __restrict__ Sc, const u16* __restrict__ Gb,
    const float* __restrict__ invFt, const float* __restrict__ invPr,
    const void* gp_, const void* gn_,
    const int* __restrict__ label, const float* __restrict__ Fvn,
    const void* Pr, float* __restrict__ out){
  __shared__ u16 a1t[64*72];
  __shared__ float agab[64], wvb[64];
  __shared__ int lab[128];
  int bid = blockIdx.x;
  int bf = detect_bf(Fs);
  int lane = threadIdx.x;
  if (bid >= 4096){
    int l = bid - 4096;
    lab[lane] = label[lane]; lab[lane + 64] = label[lane + 64];
    __syncthreads();
    float sum[8] = {0.f,0.f,0.f,0.f,0.f,0.f,0.f,0.f};
    int cnt = 0;
    for (int i = 0; i < Bn; ++i){
      if (lab[i] == l){
        cnt++;
        const float4* v = (const float4*)(Fvn + i*Cn + lane*8);
        float4 a = v[0], c = v[1];
        sum[0]+=a.x; sum[1]+=a.y; sum[2]+=a.z; sum[3]+=a.w;
        sum[4]+=c.x; sum[5]+=c.y; sum[6]+=c.z; sum[7]+=c.w;
      }
    }
    int base = l*Cn + lane*8;
    float* dst = out + 3*BL + base;
    if (cnt > 0){
      float sc = 0.01f / fmaxf((float)cnt, 1e-8f);
      #pragma unroll
      for (int j = 0; j < 8; ++j)
        dst[j] = 0.99f*(bf ? ldin<1>(Pr, base+j) : ldin<0>(Pr, base+j)) + sum[j]*sc;
    } else {
      #pragma unroll
      for (int j = 0; j < 8; ++j)
        dst[j] = bf ? ldin<1>(Pr, base+j) : ldin<0>(Pr, base+j);
    }
    return;
  }
  int qi = bid & 31, b = bid >> 5;
  int lq = lane & 15, g4 = lane >> 4;

  u32 w32[32];
  {
    const uint4* rp = (const uint4*)(Sc + ((size_t)b*VQ + qi*64 + lane)*64);
    #pragma unroll
    for (int i = 0; i < 8; ++i){
      uint4 v = rp[i];
      w32[i*4+0] = v.x; w32[i*4+1] = v.y; w32[i*4+2] = v.z; w32[i*4+3] = v.w;
    }
  }
  #define XS(s) h2f((u16)(((s)&1) ? (w32[(s)>>1] >> 16) : (w32[(s)>>1] & 0xffffu)))
  float mx = -1e30f;
  #pragma unroll
  for (int s = 0; s < Sn; ++s) mx = fmaxf(mx, XS(s));
  float raw56 = XS(56), raw57 = XS(57);
  float sm = 0.f, dx = 0.f;
  #pragma unroll
  for (int u = 0; u < 7; ++u){
    u32 pw[4];
    #pragma unroll
    for (int i = 0; i < 4; ++i){
      u32 w2 = 0;
      #pragma unroll
      for (int h = 0; h < 2; ++h){
        int s = u*8 + i*2 + h;
        float x = XS(s);
        float e = (s < Sn) ? __expf(x - mx) : 0.f;
        sm += e; dx += e * x;
        w2 |= ((u32)f2bf(e)) << (16*h);
      }
      pw[i] = w2;
    }
    *(uint4*)(a1t + lane*72 + u*8) = make_uint4(pw[0], pw[1], pw[2], pw[3]);
  }
  #undef XS

  const u16* gbase = Gb + (size_t)b*4096;
  #pragma unroll
  for (int qt = 0; qt < 4; ++qt){
    float pr[4] = {0.f, 0.f, 0.f, 0.f};
    float wvl[4] = {0.f, 0.f, 0.f, 0.f};
    #pragma unroll
    for (int nt = 0; nt < 4; ++nt){
      ffrag acc = {0.f, 0.f, 0.f, 0.f};
      #pragma unroll
      for (int kb2 = 0; kb2 < 2; ++kb2){
        bfrag af;
        if (kb2 == 1 && g4 == 3) af = (bfrag){0,0,0,0,0,0,0,0};
        else af = *(const bfrag*)(a1t + (qt*16 + lq)*72 + (g4 + 4*kb2)*8);
        bfrag bg = *(const bfrag*)(gbase + (nt*16 + lq)*64 + kb2*32 + g4*8);
        acc = __builtin_amdgcn_mfma_f32_16x16x32_bf16(af, bg, acc, 0, 0, 0);
      }
      int sp = nt*16 + lq;
      #pragma unroll
      for (int r = 0; r < 4; ++r){
        int q = qt*16 + g4*4 + r;
        float av = (sp < 56) ? bf2f(a1t[q*72 + sp]) : 0.f;
        pr[r] += av * acc[r];
        if (nt == 3 && lq == 8) wvl[r] = acc[r];
      }
    }
    #pragma unroll
    for (int m = 1; m <= 8; m <<= 1){
      #pragma unroll
      for (int r = 0; r < 4; ++r) pr[r] += __shfl_xor(pr[r], m);
    }
    if (lq == 0){
      #pragma unroll
      for (int r = 0; r < 4; ++r) agab[qt*16 + g4*4 + r] = pr[r];
    }
    if (lq == 8){
      #pragma unroll
      for (int r = 0; r < 4; ++r) wvb[qt*16 + g4*4 + r] = wvl[r];
    }
  }

  int vq = qi*64 + lane;
  int path = vq >> 10, l = vq & 1023;
  if (l < Ln){
    float gp = ld_gamma(gp_, bf), gn = ld_gamma(gn_, bf);
    float fvpSq = bf2f(gbase[56*64 + 56]);
    float inv_sm = 1.f / sm;
    float aGa = agab[lane] * inv_sm * inv_sm;
    float wv  = wvb[lane] * inv_sm;
    float gam = path ? gn : gp;
    float ns  = gam*gam*aGa + 2.f*gam*wv + fvpSq;
    float dt  = gam*(dx*inv_sm) + raw56;
    float invx = (path ? invPr : invFt)[l];
    float lg2 = dt * invx / fmaxf(sqrtf(ns), 1e-12f);
    if (path == 0){
      out[(size_t)b*Ln + l]              = raw57 * invx;
      out[(size_t)BL + (size_t)b*Ln + l] = lg2;
    } else {
      out[(size_t)2*BL + (size_t)b*Ln + l] = lg2;
    }
  }
}

// ---------------------------------------------------------------------------
extern "C" void kernel_launch(void* const* d_in, const int* in_sizes, int n_in,
                              void* d_out, int out_size, void* d_ws, size_t ws_size,
                              hipStream_t stream){
  (void)in_sizes; (void)n_in; (void)out_size; (void)ws_size;
  const void* Fs    = d_in[0];
  const void* Ft    = d_in[1];
  const void* Fv    = d_in[2];
  const int*  label = (const int*)d_in[3];
  const void* gn1g  = d_in[4];
  const void* gn1b  = d_in[5];
  const void* c1w   = d_in[6];
  const void* c1b   = d_in[7];
  const void* gn2g  = d_in[8];
  const void* gn2b  = d_in[9];
  const void* c2w   = d_in[10];
  const void* c2b   = d_in[11];
  const void* ln1g  = d_in[12];
  const void* ln1b  = d_in[13];
  const void* l1w   = d_in[14];
  const void* l1b   = d_in[15];
  const void* ln2g  = d_in[16];
  const void* ln2b  = d_in[17];
  const void* l2w   = d_in[18];
  const void* l2b   = d_in[19];
  const void* gp    = d_in[20];
  const void* gnm   = d_in[21];
  const void* proto = d_in[22];
  float* out = (float*)d_out;
  float* ws  = (float*)d_ws;

  float* m1    = ws + 0;
  float* rs1   = ws + 128;
  float* m2s   = ws + 256;
  float* m2ss  = ws + 384;
  float* invFt = ws + 512;
  float* invPr = ws + 1536;
  u16*   H1t   = (u16*)(ws + 4096);                 // B*49*512 bf16
  float* Fvp   = ws + 4096 + (size_t)Bn*Sn*Cn/2;    // B*C f32
  float* Fvn   = Fvp + Bn*Cn;
  u16*   FspAug= (u16*)(Fvn + Bn*Cn);               // B*64*512 bf16
  u16*   FtB   = FspAug + (size_t)Bn*64*512;        // 1024*512 bf16 (PrB follows)
  u16*   PrB   = FtB + (size_t)1024*512;
  u16*   Gb    = PrB + (size_t)1024*512;            // B*64*64 bf16
  u16*   W1b   = Gb + (size_t)Bn*4096;              // 512*512 bf16 x4
  u16*   W2b   = W1b + (size_t)512*512;
  u16*   W1vb  = W2b + (size_t)512*512;
  u16*   W2vb  = W1vb + (size_t)512*512;
  u16*   Hb    = W2vb + (size_t)512*512;            // 128*512 bf16
  u16*   Fsb   = Hb + (size_t)Bn*Cn;                // B*49*512 bf16
  float* Kv1a  = (float*)(Fsb + (size_t)Bn*Sn*Cn);  // 4 x 512 f32
  float* Kv1b  = Kv1a + 512;
  float* Kv2a  = Kv1b + 512;
  float* Kv2b  = Kv2a + 512;
  u16*   Sc    = (u16*)(Kv2b + 512);                // B*2048*64 f16 (33.5MB)

  k_gn1wk<<<1920, 256, 0, stream>>>(Fs, c1w, c2w, l1w, l2w, gn1g, gn2g,
                                    gn1b, gn2b, c1b, c2b,
                                    W1b, W2b, W1vb, W2vb, Kv1a, Kv1b, Kv2a, Kv2b,
                                    Ft, proto, invFt, invPr, FtB, PrB,
                                    m1, rs1, Fsb, m2s, m2ss);
  k_c1vg1<<<288, 512, 0, stream>>>(Fs, Fsb, W1b, Kv1a, Kv1b, m1, rs1, H1t, m2s, m2ss,
                                   Fv, ln1g, ln1b, W1vb, l1b, Hb);
  k_c2vg2<<<288, 512, 0, stream>>>(Fs, H1t, W2b, Kv2a, Kv2b, m2s, m2ss, FspAug,
                                   Hb, ln2g, ln2b, W2vb, l2b, Fvp);
  k_prep<<<Bn, 256, 0, stream>>>(Fvp, Fvn, FspAug, Gb);
  k_scores<<<dim3(Bn, 8), 256, 0, stream>>>(FtB, FspAug, Sc);
  k_attn4<<<4096 + Ln, 64, 0, stream>>>(Fs, Sc, Gb, invFt, invPr, gp, gnm,
                                        label, Fvn, proto, out);
}

// Round 20
// 146.292 us; speedup vs baseline: 1.1305x; 1.1305x over previous
//
#include <hip/hip_runtime.h>

// ---------------------------------------------------------------------------
// DPM_Block — Round 20: revert to R18 (141.2us proven; R19's 512-thread conv
// hit a VGPR=64 spill cliff: WRITE 13->109MB scratch). Single retained change:
// k_scores launch_bounds (256,4) (VGPR 64 -> no spill risk, +occupancy).
// ---------------------------------------------------------------------------

#define Bn 128
#define Sn 49
#define Cn 512
#define Ln 1000
#define BL (Bn*Ln)
#define VQ 2048

typedef unsigned short u16;
typedef unsigned int u32;

using bfrag = __attribute__((ext_vector_type(8))) short;   // 8 bf16 (4 VGPR)
using ffrag = __attribute__((ext_vector_type(4))) float;   // 4 f32 acc

typedef const __attribute__((address_space(1))) u32 gq_t;
typedef __attribute__((address_space(3))) u32 lq_t;

__device__ __forceinline__ float bf2f(u16 u){ return __uint_as_float(((u32)u) << 16); }
__device__ __forceinline__ float bflo(u32 u){ return __uint_as_float(u << 16); }
__device__ __forceinline__ float bfhi(u32 u){ return __uint_as_float(u & 0xffff0000u); }
__device__ __forceinline__ u16 f2bf(float f){
  u32 x = __float_as_uint(f);
  u32 r = x + 0x7fffu + ((x >> 16) & 1u);   // RNE
  return (u16)(r >> 16);
}
__device__ __forceinline__ u16 f2h(float f){
  _Float16 h = (_Float16)f; return *(u16*)&h;
}
__device__ __forceinline__ float h2f(u16 u){
  _Float16 h = *(_Float16*)&u; return (float)h;
}

template<int BF>
__device__ __forceinline__ float ldin(const void* p, int i){
  if (BF) return bf2f(((const u16*)p)[i]);
  return ((const float*)p)[i];
}

template<int BF>
__device__ __forceinline__ void ld8(const void* p, int base, float* w){
  if (BF){
    uint4 u = *(const uint4*)((const u16*)p + base);
    w[0]=bflo(u.x); w[1]=bfhi(u.x); w[2]=bflo(u.y); w[3]=bfhi(u.y);
    w[4]=bflo(u.z); w[5]=bfhi(u.z); w[6]=bflo(u.w); w[7]=bfhi(u.w);
  } else {
    float4 a = *(const float4*)((const float*)p + base);
    float4 b = *(const float4*)((const float*)p + base + 4);
    w[0]=a.x; w[1]=a.y; w[2]=a.z; w[3]=a.w;
    w[4]=b.x; w[5]=b.y; w[6]=b.z; w[7]=b.w;
  }
}

__device__ __forceinline__ uint4 pack8(const float* w){
  uint4 v;
  v.x = (u32)f2bf(w[0]) | ((u32)f2bf(w[1])<<16);
  v.y = (u32)f2bf(w[2]) | ((u32)f2bf(w[3])<<16);
  v.z = (u32)f2bf(w[4]) | ((u32)f2bf(w[5])<<16);
  v.w = (u32)f2bf(w[6]) | ((u32)f2bf(w[7])<<16);
  return v;
}

__device__ __forceinline__ float ld_gamma(const void* p, int BF){
  float fb = bf2f(((const u16*)p)[0]);
  float ff = ((const float*)p)[0];
  bool pb = (fb > 0.05f && fb < 1.5f);
  bool pf = (ff > 0.05f && ff < 1.5f);
  if (pb && !pf) return fb;
  if (pf && !pb) return ff;
  return BF ? fb : ff;
}

// ---- inline dtype detector ----
__device__ __forceinline__ int detect_bf(const void* Fs){
  int lane = threadIdx.x & 63;
  uint4 v = ((const uint4*)Fs)[lane];
  u32 w[4] = {v.x, v.y, v.z, v.w};
  int c = 0;
  #pragma unroll
  for (int j = 0; j < 4; ++j){
    int e = (w[j] >> 7) & 0xff;
    c += (e >= 0x70 && e <= 0x8f);
  }
  #pragma unroll
  for (int m = 32; m; m >>= 1) c += __shfl_xor(c, m);
  return c >= 200;
}

__device__ __forceinline__ float2 block_red2(float a, float b, float* scratch){
  __syncthreads();
  #pragma unroll
  for (int off = 32; off; off >>= 1){ a += __shfl_xor(a, off); b += __shfl_xor(b, off); }
  int lane = threadIdx.x & 63, wid = threadIdx.x >> 6;
  if (lane == 0){ scratch[wid] = a; scratch[wid + 4] = b; }
  __syncthreads();
  return make_float2(scratch[0] + scratch[1] + scratch[2] + scratch[3],
                     scratch[4] + scratch[5] + scratch[6] + scratch[7]);
}

// -------------------- bodies --------------------
template<int BF>
__device__ void gn1_body(int b, const void* Fs, float* m1, float* rs1, u16* Fsb,
                         float* m2s, float* m2ss, float* red){
  int tid = threadIdx.x;
  if (tid == 0){ m2s[b] = 0.f; m2ss[b] = 0.f; }
  float s = 0.f, ss = 0.f;
  for (int i = tid; i < Sn*Cn/8; i += 256){
    float w[8]; ld8<BF>(Fs, b*Sn*Cn + i*8, w);
    #pragma unroll
    for (int j = 0; j < 8; ++j){ s += w[j]; ss += w[j]*w[j]; }
    *(uint4*)(Fsb + (size_t)b*Sn*Cn + i*8) = pack8(w);
  }
  float2 r = block_red2(s, ss, red);
  if (tid == 0){
    float m = r.x * (1.f/(Sn*Cn));
    float v = r.y * (1.f/(Sn*Cn)) - m*m;
    m1[b] = m; rs1[b] = rsqrtf(v + 1e-5f);
  }
}

template<int BF>
__device__ void wk_body(int blk, const void* W1, const void* W2, const void* W3,
    const void* W4, const void* g1, const void* g2, const void* bb1, const void* bb2,
    const void* bias1, const void* bias2,
    u16* D1, u16* D2, u16* D3, u16* D4,
    float* K1a, float* K1b, float* K2a, float* K2b){
  if (blk < 512){
    int i = blk*256 + threadIdx.x;
    int sel = i >> 15;
    const void* src = (sel==0) ? W1 : (sel==1) ? W2 : (sel==2) ? W3 : W4;
    u16* dst = (sel==0) ? D1 : (sel==1) ? D2 : (sel==2) ? D3 : D4;
    int off = (i & 32767)*8;
    float w[8]; ld8<BF>(src, off, w);
    if (sel <= 1){
      const void* g = sel ? g2 : g1;
      int c0 = off & 511;
      #pragma unroll
      for (int j = 0; j < 8; ++j) w[j] *= ldin<BF>(g, c0 + j);
    }
    *(uint4*)(dst + off) = pack8(w);
  } else {
    int idx = (blk - 512)*4 + (threadIdx.x >> 6);
    int lane = threadIdx.x & 63;
    int o = idx & 511, sel = idx >> 9;
    const void* W  = sel ? W2 : W1;
    const void* g  = sel ? g2 : g1;
    const void* bb = sel ? bb2 : bb1;
    const void* bi = sel ? bias2 : bias1;
    float* Ka = sel ? K2a : K1a;
    float* Kb = sel ? K2b : K1b;
    float w[8], gv[8], bv[8];
    ld8<BF>(W, o*Cn + lane*8, w);
    ld8<BF>(g, lane*8, gv);
    ld8<BF>(bb, lane*8, bv);
    float a = 0.f, b2 = 0.f;
    #pragma unroll
    for (int j = 0; j < 8; ++j){ a += w[j]*bv[j]; b2 += w[j]*gv[j]; }
    #pragma unroll
    for (int m = 32; m; m >>= 1){ a += __shfl_xor(a, m); b2 += __shfl_xor(b2, m); }
    if (lane == 0){ Ka[o] = a + ldin<BF>(bi, o); Kb[o] = b2; }
  }
}

template<int BF>
__device__ void protonorm_body(int l, const void* Ft, const void* Pr,
                               float* invFt, float* invPr,
                               u16* FtB, u16* PrB, float* red){
  int tid = threadIdx.x;
  if (l >= Ln){
    FtB[(size_t)l*512 + tid] = 0; FtB[(size_t)l*512 + tid + 256] = 0;
    PrB[(size_t)l*512 + tid] = 0; PrB[(size_t)l*512 + tid + 256] = 0;
    return;
  }
  float a0 = ldin<BF>(Ft, l*Cn + tid), a1 = ldin<BF>(Ft, l*Cn + tid + 256);
  float p0 = ldin<BF>(Pr, l*Cn + tid), p1 = ldin<BF>(Pr, l*Cn + tid + 256);
  FtB[(size_t)l*512 + tid] = f2bf(a0); FtB[(size_t)l*512 + tid + 256] = f2bf(a1);
  PrB[(size_t)l*512 + tid] = f2bf(p0); PrB[(size_t)l*512 + tid + 256] = f2bf(p1);
  float2 r = block_red2(a0*a0 + a1*a1, p0*p0 + p1*p1, red);
  if (tid == 0){
    invFt[l] = 1.f / fmaxf(sqrtf(r.x), 1e-12f);
    invPr[l] = 1.f / fmaxf(sqrtf(r.y), 1e-12f);
  }
}

// ---- launch 1: [0,512) wconv, [512,768) kvec, [768,1792) protonorm,
//      [1792,1920) gn1 ----
__global__ __launch_bounds__(256) void k_gn1wk(const void* Fs,
    const void* W1, const void* W2, const void* W3, const void* W4,
    const void* g1, const void* g2, const void* bb1, const void* bb2,
    const void* bias1, const void* bias2,
    u16* D1, u16* D2, u16* D3, u16* D4,
    float* K1a, float* K1b, float* K2a, float* K2b,
    const void* Ft, const void* Pr, float* invFt, float* invPr, u16* FtB, u16* PrB,
    float* m1, float* rs1, u16* Fsb, float* m2s, float* m2ss){
  __shared__ float red[8];
  int bf = detect_bf(Fs);
  int blk = blockIdx.x;
  if (blk < 768){
    if (bf) wk_body<1>(blk, W1, W2, W3, W4, g1, g2, bb1, bb2, bias1, bias2,
                       D1, D2, D3, D4, K1a, K1b, K2a, K2b);
    else    wk_body<0>(blk, W1, W2, W3, W4, g1, g2, bb1, bb2, bias1, bias2,
                       D1, D2, D3, D4, K1a, K1b, K2a, K2b);
  } else if (blk < 1792){
    int l = blk - 768;
    if (bf) protonorm_body<1>(l, Ft, Pr, invFt, invPr, FtB, PrB, red);
    else    protonorm_body<0>(l, Ft, Pr, invFt, invPr, FtB, PrB, red);
  } else {
    int b = blk - 1792;
    if (bf) gn1_body<1>(b, Fs, m1, rs1, Fsb, m2s, m2ss, red);
    else    gn1_body<0>(b, Fs, m1, rs1, Fsb, m2s, m2ss, red);
  }
}

// ------- MFMA conv body (GN folded), b/o0 passed in (256 threads) -----------
template<int C1>
__device__ void convm_body(int b, int o0,
    const u16* __restrict__ src, const u16* __restrict__ Wb,
    const float* __restrict__ Ka, const float* __restrict__ Kb,
    float mean, float rs, u16* dst, u16* Bs, float* red,
    float* m2s, float* m2ss){
  int tid = threadIdx.x;
  int lane = tid & 63, wid = tid >> 6, lq = lane & 15, g4 = lane >> 4;
  for (int idx = tid; idx < 15*64; idx += 256){
    int r = 49 + (idx >> 6), j = idx & 63;
    *(uint4*)(Bs + (r<<9) + (j<<3)) = (uint4){0,0,0,0};
  }
  #pragma unroll
  for (int is = 0; is < 13; ++is){
    int r = is*4 + wid;
    if (r < Sn){
      const u16* gsrc = src + (size_t)(b*Sn + r)*Cn + ((lane ^ (r & 7)) << 3);
      u16* ldst = Bs + (r << 9);
      __builtin_amdgcn_global_load_lds((gq_t*)gsrc, (lq_t*)ldst, 16, 0, 0);
    }
  }
  __syncthreads();
  float gs = 0.f, gss = 0.f;
  #pragma unroll
  for (int ot = 0; ot < 2; ++ot){
    int oA = o0 + wid*32 + ot*16;
    bfrag af[16];
    #pragma unroll
    for (int kb = 0; kb < 16; ++kb)
      af[kb] = *(const bfrag*)(Wb + (size_t)(oA + lq)*Cn + kb*32 + g4*8);
    ffrag acc[4];
    #pragma unroll
    for (int st = 0; st < 4; ++st) acc[st] = (ffrag){0.f,0.f,0.f,0.f};
    #pragma unroll
    for (int st = 0; st < 4; ++st){
      int srow = st*16 + lq;
      #pragma unroll
      for (int kb = 0; kb < 16; ++kb){
        bfrag bf_ = *(const bfrag*)(Bs + (srow<<9) + (((kb*4+g4) ^ (srow&7))<<3));
        acc[st] = __builtin_amdgcn_mfma_f32_16x16x32_bf16(af[kb], bf_, acc[st], 0,0,0);
      }
    }
    int ob = oA + g4*4;
    float cst[4];
    #pragma unroll
    for (int r = 0; r < 4; ++r) cst[r] = Ka[ob + r] - mean*rs*Kb[ob + r];
    #pragma unroll
    for (int st = 0; st < 4; ++st){
      int s = st*16 + lq;
      u16 pk[4];
      #pragma unroll
      for (int r = 0; r < 4; ++r){
        float val = rs*acc[st][r] + cst[r];
        if (C1){
          val = fmaxf(val, 0.f);
          if (s < Sn){ gs += val; gss += val*val; }
        }
        pk[r] = f2bf(val);
      }
      if (C1){
        if (s < Sn) *(uint2*)(dst + ((size_t)(b*Sn + s)<<9) + ob) = *(const uint2*)pk;
      } else {
        if (s >= Sn){ pk[0]=0; pk[1]=0; pk[2]=0; pk[3]=0; }
        *(uint2*)(dst + ((size_t)(b*64 + s)<<9) + ob) = *(const uint2*)pk;
      }
    }
  }
  if (C1){
    float2 r2 = block_red2(gs, gss, red);
    if (tid == 0){
      atomicAdd(&m2s[b], r2.x);
      atomicAdd(&m2ss[b], r2.y);
    }
  }
}

// ------------- vector MLP body, o0 passed in (256 threads) ------------------
template<int BF, int SBF, int PH>
__device__ void vg_body(int o0, const void* src, const void* lng, const void* lnb,
    const u16* __restrict__ Wv, const void* bias, void* outp,
    u16* Bt, u16* Ach, float* mrow, float* rrow, float* Gc, float* Bc2){
  int tid = threadIdx.x, lane = tid & 63, wid = tid >> 6;
  int lq = lane & 15, g4 = lane >> 4;
  for (int c = tid; c < Cn; c += 256){ Gc[c] = ldin<BF>(lng, c); Bc2[c] = ldin<BF>(lnb, c); }
  {
    int r = tid >> 1, h = tid & 1;
    float s = 0.f, ss = 0.f;
    #pragma unroll 4
    for (int k = 0; k < 32; ++k){
      float w[8]; ld8<SBF>(src, r*Cn + h*256 + k*8, w);
      #pragma unroll
      for (int j = 0; j < 8; ++j){ s += w[j]; ss += w[j]*w[j]; }
    }
    s += __shfl_xor(s, 1); ss += __shfl_xor(ss, 1);
    if (h == 0){
      float m = s * (1.f/Cn);
      mrow[r] = m; rrow[r] = rsqrtf(ss * (1.f/Cn) - m*m + 1e-5f);
    }
  }
  for (int idx = tid; idx < 16*64; idx += 256){
    int row = idx >> 6, j = idx & 63;
    uint4 v = *(const uint4*)(Wv + (size_t)(o0 + row)*Cn + j*8);
    *(uint4*)(Bt + (row<<9) + ((j ^ (row&7))<<3)) = v;
  }
  __syncthreads();
  ffrag acc[2];
  acc[0] = (ffrag){0.f,0.f,0.f,0.f};
  acc[1] = (ffrag){0.f,0.f,0.f,0.f};
  for (int kc = 0; kc < 4; ++kc){
    if (kc) __syncthreads();
    for (int idx = tid; idx < 128*16; idx += 256){
      int row = idx >> 4, j = idx & 15;
      int c = kc*128 + j*8;
      float w[8]; ld8<SBF>(src, row*Cn + c, w);
      float mu = mrow[row], rsd = rrow[row];
      #pragma unroll
      for (int k2 = 0; k2 < 8; ++k2) w[k2] = (w[k2]-mu)*rsd*Gc[c+k2] + Bc2[c+k2];
      *(uint4*)(Ach + (row<<7) + ((j ^ (row&15))<<3)) = pack8(w);
    }
    __syncthreads();
    #pragma unroll
    for (int mt2 = 0; mt2 < 2; ++mt2){
      int arow = (wid*2 + mt2)*16 + lq;
      #pragma unroll
      for (int kb = 0; kb < 4; ++kb){
        bfrag af = *(const bfrag*)(Ach + (arow<<7) + (((kb*4+g4) ^ (arow&15))<<3));
        bfrag bf_ = *(const bfrag*)(Bt + (lq<<9) + (((kc*16 + kb*4 + g4) ^ (lq&7))<<3));
        acc[mt2] = __builtin_amdgcn_mfma_f32_16x16x32_bf16(af, bf_, acc[mt2], 0,0,0);
      }
    }
  }
  float bval = ldin<BF>(bias, o0 + lq);
  #pragma unroll
  for (int mt2 = 0; mt2 < 2; ++mt2){
    #pragma unroll
    for (int r = 0; r < 4; ++r){
      int brow = wid*32 + mt2*16 + g4*4 + r;
      float val = acc[mt2][r] + bval;
      if (PH == 1){
        ((u16*)outp)[brow*Cn + o0 + lq] = f2bf(fmaxf(val, 0.f));
      } else {
        ((float*)outp)[brow*Cn + o0 + lq] = val;
      }
    }
  }
}

// LDS union: conv = 64KB Bs + 32B red; vg = 53KB carved
#define CV_SHARED __shared__ __align__(16) char smu[65568];

// ---- launch 2: vg1 (blocks 0..31) + conv1m (32..543) ----
__global__ __launch_bounds__(256, 2) void k_c1vg1(const void* Fs,
    const u16* Fsb, const u16* W1b, const float* Ka, const float* Kb,
    const float* m1, const float* rs1, u16* H1t, float* m2s, float* m2ss,
    const void* Fv, const void* ln1g, const void* ln1b,
    const u16* W1vb, const void* l1b, u16* Hb){
  CV_SHARED
  int blk = blockIdx.x;
  if (blk >= 32){
    u16* Bs = (u16*)smu;
    float* red = (float*)(smu + 65536);
    int cb = blk - 32;
    int b = cb >> 2, o0 = (cb & 3)*128;
    convm_body<1>(b, o0, Fsb, W1b, Ka, Kb, m1[b], rs1[b], H1t, Bs, red, m2s, m2ss);
  } else {
    u16* Bt = (u16*)smu;
    u16* Ach = (u16*)(smu + 16384);
    float* mrow = (float*)(smu + 49152);
    float* rrow = (float*)(smu + 49664);
    float* Gc = (float*)(smu + 50176);
    float* Bc2 = (float*)(smu + 52224);
    int o0 = blk*16;
    if (detect_bf(Fs)) vg_body<1,1,1>(o0, Fv, ln1g, ln1b, W1vb, l1b, Hb, Bt, Ach, mrow, rrow, Gc, Bc2);
    else               vg_body<0,0,1>(o0, Fv, ln1g, ln1b, W1vb, l1b, Hb, Bt, Ach, mrow, rrow, Gc, Bc2);
  }
}

// ---- launch 3: vg2 (blocks 0..31) + conv2m (32..543) ----
__global__ __launch_bounds__(256, 2) void k_c2vg2(const void* Fs,
    const u16* H1t, const u16* W2b, const float* Ka, const float* Kb,
    const float* m2s, const float* m2ss, u16* FspAug,
    const u16* Hb, const void* ln2g, const void* ln2b,
    const u16* W2vb, const void* l2b, float* Y2){
  CV_SHARED
  int blk = blockIdx.x;
  if (blk >= 32){
    u16* Bs = (u16*)smu;
    int cb = blk - 32;
    int b = cb >> 2, o0 = (cb & 3)*128;
    float sum = m2s[b], ssum = m2ss[b];
    float mean = sum * (1.f/(Sn*Cn));
    float var  = ssum * (1.f/(Sn*Cn)) - mean*mean;
    float rs = rsqrtf(var + 1e-5f);
    convm_body<0>(b, o0, H1t, W2b, Ka, Kb, mean, rs, FspAug, Bs,
                  (float*)nullptr, (float*)nullptr, (float*)nullptr);
  } else {
    u16* Bt = (u16*)smu;
    u16* Ach = (u16*)(smu + 16384);
    float* mrow = (float*)(smu + 49152);
    float* rrow = (float*)(smu + 49664);
    float* Gc = (float*)(smu + 50176);
    float* Bc2 = (float*)(smu + 52224);
    int o0 = blk*16;
    if (detect_bf(Fs)) vg_body<1,1,2>(o0, Hb, ln2g, ln2b, W2vb, l2b, Y2, Bt, Ach, mrow, rrow, Gc, Bc2);
    else               vg_body<0,1,2>(o0, Hb, ln2g, ln2b, W2vb, l2b, Y2, Bt, Ach, mrow, rrow, Gc, Bc2);
  }
}

// --- k_prep: Fvn = l2norm(Fvp) (fused); aug rows 56/57; G = Aug·Aug^T -------
__global__ __launch_bounds__(256) void k_prep(const float* __restrict__ Fvp,
    float* __restrict__ Fvn, u16* __restrict__ FspAug, u16* __restrict__ Gb){
  __shared__ u16 xa[64*512];
  __shared__ float red[8];
  __shared__ float fvrow[512];
  int b = blockIdx.x, tid = threadIdx.x;
  int lane = tid & 63, wid = tid >> 6, lq = lane & 15, g4 = lane >> 4;
  float x0 = Fvp[b*Cn + tid], x1 = Fvp[b*Cn + tid + 256];
  float2 rr = block_red2(x0*x0 + x1*x1, 0.f, red);
  float inv = 1.f / fmaxf(sqrtf(rr.x), 1e-12f);
  fvrow[tid] = x0*inv; fvrow[tid + 256] = x1*inv;
  Fvn[b*Cn + tid] = x0*inv; Fvn[b*Cn + tid + 256] = x1*inv;
  __syncthreads();
  for (int idx = tid; idx < 64*64; idx += 256){
    int s = idx >> 6, j = idx & 63;
    uint4 v;
    if (s == 56 || s == 57){
      float w[8];
      if (s == 56){
        const float* src = Fvp + b*Cn + j*8;
        #pragma unroll
        for (int k = 0; k < 8; ++k) w[k] = src[k];
      } else {
        #pragma unroll
        for (int k = 0; k < 8; ++k) w[k] = fvrow[j*8 + k];
      }
      v = pack8(w);
      *(uint4*)(FspAug + ((size_t)(b*64 + s))*512 + j*8) = v;
    } else {
      v = *(const uint4*)(FspAug + ((size_t)(b*64 + s))*512 + j*8);
    }
    *(uint4*)(xa + s*512 + ((j ^ (s&7)) << 3)) = v;
  }
  __syncthreads();
  int mt = wid;
  for (int nt = 0; nt < 4; ++nt){
    ffrag acc = {0.f, 0.f, 0.f, 0.f};
    #pragma unroll
    for (int kb = 0; kb < 16; ++kb){
      int j = kb*4 + g4;
      int rowa = mt*16 + lq, rowb = nt*16 + lq;
      bfrag af  = *(const bfrag*)(xa + rowa*512 + ((j ^ (rowa&7)) << 3));
      bfrag bf_ = *(const bfrag*)(xa + rowb*512 + ((j ^ (rowb&7)) << 3));
      acc = __builtin_amdgcn_mfma_f32_16x16x32_bf16(af, bf_, acc, 0, 0, 0);
    }
    #pragma unroll
    for (int r = 0; r < 4; ++r)
      Gb[(size_t)b*4096 + (mt*16 + g4*4 + r)*64 + nt*16 + lq] = f2bf(acc[r]);
  }
}

// ------- K1: scores GEMM -> f16; async staging; grid (Bn, 8) ---------------
__global__ __launch_bounds__(256, 4) void k_scores(const u16* __restrict__ LB,
    const u16* __restrict__ FspAug, u16* __restrict__ Sc){
  __shared__ u16 At[64*256];   // 32768 B
  int b = blockIdx.x, lg = blockIdx.y;
  int tid = threadIdx.x, lane = tid & 63, wid = tid >> 6;
  int lq = lane & 15, g4 = lane >> 4;
  int l32 = lane & 31, rh = lane >> 5;
  bfrag breg[16];
  {
    const u16* fa = FspAug + ((size_t)(b*64 + wid*16 + lq))*512 + g4*8;
    #pragma unroll
    for (int kb = 0; kb < 16; ++kb) breg[kb] = *(const bfrag*)(fa + kb*32);
  }
  for (int chunk = 0; chunk < 4; ++chunk){
    int qi = lg*4 + chunk;
    ffrag acc[4];
    #pragma unroll
    for (int lt = 0; lt < 4; ++lt) acc[lt] = (ffrag){0.f,0.f,0.f,0.f};
    for (int kc = 0; kc < 2; ++kc){
      __syncthreads();   // guard At rewrite
      #pragma unroll
      for (int is = 0; is < 8; ++is){
        int r = (is*4 + wid)*2 + rh;
        const u16* gsrc = LB + (size_t)(qi*64 + r)*512 + kc*256 + ((l32 ^ (r & 7)) << 3);
        u16* ldst = At + ((is*4 + wid) << 9);
        __builtin_amdgcn_global_load_lds((gq_t*)gsrc, (lq_t*)ldst, 16, 0, 0);
      }
      __syncthreads();
      #pragma unroll
      for (int kb = 0; kb < 8; ++kb){
        #pragma unroll
        for (int lt = 0; lt < 4; ++lt){
          int row = lt*16 + lq;
          bfrag af = *(const bfrag*)(At + (row<<8) + (((kb*4+g4) ^ (row&7))<<3));
          acc[lt] = __builtin_amdgcn_mfma_f32_16x16x32_bf16(af, breg[kc*8+kb], acc[lt], 0,0,0);
        }
      }
    }
    #pragma unroll
    for (int lt = 0; lt < 4; ++lt){
      #pragma unroll
      for (int r = 0; r < 4; ++r){
        size_t row = (size_t)b*VQ + qi*64 + lt*16 + g4*4 + r;
        Sc[row*64 + wid*16 + lq] = f2h(acc[lt][r]);
      }
    }
  }
}

// -- K2: row-per-lane softmax + gram epilogue; blocks >= 4096 do proto update
__global__ __launch_bounds__(64) void k_attn4(const void* Fs,
    const u16* __restrict__ Sc, const u16* __restrict__ Gb,
    const float* __restrict__ invFt, const float* __restrict__ invPr,
    const void* gp_, const void* gn_,
    const int* __restrict__ label, const float* __restrict__ Fvn,
    const void* Pr, float* __restrict__ out){
  __shared__ u16 a1t[64*72];
  __shared__ float agab[64], wvb[64];
  __shared__ int lab[128];
  int bid = blockIdx.x;
  int bf = detect_bf(Fs);
  int lane = threadIdx.x;
  if (bid >= 4096){
    int l = bid - 4096;
    lab[lane] = label[lane]; lab[lane + 64] = label[lane + 64];
    __syncthreads();
    float sum[8] = {0.f,0.f,0.f,0.f,0.f,0.f,0.f,0.f};
    int cnt = 0;
    for (int i = 0; i < Bn; ++i){
      if (lab[i] == l){
        cnt++;
        const float4* v = (const float4*)(Fvn + i*Cn + lane*8);
        float4 a = v[0], c = v[1];
        sum[0]+=a.x; sum[1]+=a.y; sum[2]+=a.z; sum[3]+=a.w;
        sum[4]+=c.x; sum[5]+=c.y; sum[6]+=c.z; sum[7]+=c.w;
      }
    }
    int base = l*Cn + lane*8;
    float* dst = out + 3*BL + base;
    if (cnt > 0){
      float sc = 0.01f / fmaxf((float)cnt, 1e-8f);
      #pragma unroll
      for (int j = 0; j < 8; ++j)
        dst[j] = 0.99f*(bf ? ldin<1>(Pr, base+j) : ldin<0>(Pr, base+j)) + sum[j]*sc;
    } else {
      #pragma unroll
      for (int j = 0; j < 8; ++j)
        dst[j] = bf ? ldin<1>(Pr, base+j) : ldin<0>(Pr, base+j);
    }
    return;
  }
  int qi = bid & 31, b = bid >> 5;
  int lq = lane & 15, g4 = lane >> 4;

  u32 w32[32];
  {
    const uint4* rp = (const uint4*)(Sc + ((size_t)b*VQ + qi*64 + lane)*64);
    #pragma unroll
    for (int i = 0; i < 8; ++i){
      uint4 v = rp[i];
      w32[i*4+0] = v.x; w32[i*4+1] = v.y; w32[i*4+2] = v.z; w32[i*4+3] = v.w;
    }
  }
  #define XS(s) h2f((u16)(((s)&1) ? (w32[(s)>>1] >> 16) : (w32[(s)>>1] & 0xffffu)))
  float mx = -1e30f;
  #pragma unroll
  for (int s = 0; s < Sn; ++s) mx = fmaxf(mx, XS(s));
  float raw56 = XS(56), raw57 = XS(57);
  float sm = 0.f, dx = 0.f;
  #pragma unroll
  for (int u = 0; u < 7; ++u){
    u32 pw[4];
    #pragma unroll
    for (int i = 0; i < 4; ++i){
      u32 w2 = 0;
      #pragma unroll
      for (int h = 0; h < 2; ++h){
        int s = u*8 + i*2 + h;
        float x = XS(s);
        float e = (s < Sn) ? __expf(x - mx) : 0.f;
        sm += e; dx += e * x;
        w2 |= ((u32)f2bf(e)) << (16*h);
      }
      pw[i] = w2;
    }
    *(uint4*)(a1t + lane*72 + u*8) = make_uint4(pw[0], pw[1], pw[2], pw[3]);
  }
  #undef XS

  const u16* gbase = Gb + (size_t)b*4096;
  #pragma unroll
  for (int qt = 0; qt < 4; ++qt){
    float pr[4] = {0.f, 0.f, 0.f, 0.f};
    float wvl[4] = {0.f, 0.f, 0.f, 0.f};
    #pragma unroll
    for (int nt = 0; nt < 4; ++nt){
      ffrag acc = {0.f, 0.f, 0.f, 0.f};
      #pragma unroll
      for (int kb2 = 0; kb2 < 2; ++kb2){
        bfrag af;
        if (kb2 == 1 && g4 == 3) af = (bfrag){0,0,0,0,0,0,0,0};
        else af = *(const bfrag*)(a1t + (qt*16 + lq)*72 + (g4 + 4*kb2)*8);
        bfrag bg = *(const bfrag*)(gbase + (nt*16 + lq)*64 + kb2*32 + g4*8);
        acc = __builtin_amdgcn_mfma_f32_16x16x32_bf16(af, bg, acc, 0, 0, 0);
      }
      int sp = nt*16 + lq;
      #pragma unroll
      for (int r = 0; r < 4; ++r){
        int q = qt*16 + g4*4 + r;
        float av = (sp < 56) ? bf2f(a1t[q*72 + sp]) : 0.f;
        pr[r] += av * acc[r];
        if (nt == 3 && lq == 8) wvl[r] = acc[r];
      }
    }
    #pragma unroll
    for (int m = 1; m <= 8; m <<= 1){
      #pragma unroll
      for (int r = 0; r < 4; ++r) pr[r] += __shfl_xor(pr[r], m);
    }
    if (lq == 0){
      #pragma unroll
      for (int r = 0; r < 4; ++r) agab[qt*16 + g4*4 + r] = pr[r];
    }
    if (lq == 8){
      #pragma unroll
      for (int r = 0; r < 4; ++r) wvb[qt*16 + g4*4 + r] = wvl[r];
    }
  }

  int vq = qi*64 + lane;
  int path = vq >> 10, l = vq & 1023;
  if (l < Ln){
    float gp = ld_gamma(gp_, bf), gn = ld_gamma(gn_, bf);
    float fvpSq = bf2f(gbase[56*64 + 56]);
    float inv_sm = 1.f / sm;
    float aGa = agab[lane] * inv_sm * inv_sm;
    float wv  = wvb[lane] * inv_sm;
    float gam = path ? gn : gp;
    float ns  = gam*gam*aGa + 2.f*gam*wv + fvpSq;
    float dt  = gam*(dx*inv_sm) + raw56;
    float invx = (path ? invPr : invFt)[l];
    float lg2 = dt * invx / fmaxf(sqrtf(ns), 1e-12f);
    if (path == 0){
      out[(size_t)b*Ln + l]              = raw57 * invx;
      out[(size_t)BL + (size_t)b*Ln + l] = lg2;
    } else {
      out[(size_t)2*BL + (size_t)b*Ln + l] = lg2;
    }
  }
}

// ---------------------------------------------------------------------------
extern "C" void kernel_launch(void* const* d_in, const int* in_sizes, int n_in,
                              void* d_out, int out_size, void* d_ws, size_t ws_size,
                              hipStream_t stream){
  (void)in_sizes; (void)n_in; (void)out_size; (void)ws_size;
  const void* Fs    = d_in[0];
  const void* Ft    = d_in[1];
  const void* Fv    = d_in[2];
  const int*  label = (const int*)d_in[3];
  const void* gn1g  = d_in[4];
  const void* gn1b  = d_in[5];
  const void* c1w   = d_in[6];
  const void* c1b   = d_in[7];
  const void* gn2g  = d_in[8];
  const void* gn2b  = d_in[9];
  const void* c2w   = d_in[10];
  const void* c2b   = d_in[11];
  const void* ln1g  = d_in[12];
  const void* ln1b  = d_in[13];
  const void* l1w   = d_in[14];
  const void* l1b   = d_in[15];
  const void* ln2g  = d_in[16];
  const void* ln2b  = d_in[17];
  const void* l2w   = d_in[18];
  const void* l2b   = d_in[19];
  const void* gp    = d_in[20];
  const void* gnm   = d_in[21];
  const void* proto = d_in[22];
  float* out = (float*)d_out;
  float* ws  = (float*)d_ws;

  float* m1    = ws + 0;
  float* rs1   = ws + 128;
  float* m2s   = ws + 256;
  float* m2ss  = ws + 384;
  float* invFt = ws + 512;
  float* invPr = ws + 1536;
  u16*   H1t   = (u16*)(ws + 4096);                 // B*49*512 bf16
  float* Fvp   = ws + 4096 + (size_t)Bn*Sn*Cn/2;    // B*C f32
  float* Fvn   = Fvp + Bn*Cn;
  u16*   FspAug= (u16*)(Fvn + Bn*Cn);               // B*64*512 bf16
  u16*   FtB   = FspAug + (size_t)Bn*64*512;        // 1024*512 bf16 (PrB follows)
  u16*   PrB   = FtB + (size_t)1024*512;
  u16*   Gb    = PrB + (size_t)1024*512;            // B*64*64 bf16
  u16*   W1b   = Gb + (size_t)Bn*4096;              // 512*512 bf16 x4
  u16*   W2b   = W1b + (size_t)512*512;
  u16*   W1vb  = W2b + (size_t)512*512;
  u16*   W2vb  = W1vb + (size_t)512*512;
  u16*   Hb    = W2vb + (size_t)512*512;            // 128*512 bf16
  u16*   Fsb   = Hb + (size_t)Bn*Cn;                // B*49*512 bf16
  float* Kv1a  = (float*)(Fsb + (size_t)Bn*Sn*Cn);  // 4 x 512 f32
  float* Kv1b  = Kv1a + 512;
  float* Kv2a  = Kv1b + 512;
  float* Kv2b  = Kv2a + 512;
  u16*   Sc    = (u16*)(Kv2b + 512);                // B*2048*64 f16 (33.5MB)

  k_gn1wk<<<1920, 256, 0, stream>>>(Fs, c1w, c2w, l1w, l2w, gn1g, gn2g,
                                    gn1b, gn2b, c1b, c2b,
                                    W1b, W2b, W1vb, W2vb, Kv1a, Kv1b, Kv2a, Kv2b,
                                    Ft, proto, invFt, invPr, FtB, PrB,
                                    m1, rs1, Fsb, m2s, m2ss);
  k_c1vg1<<<544, 256, 0, stream>>>(Fs, Fsb, W1b, Kv1a, Kv1b, m1, rs1, H1t, m2s, m2ss,
                                   Fv, ln1g, ln1b, W1vb, l1b, Hb);
  k_c2vg2<<<544, 256, 0, stream>>>(Fs, H1t, W2b, Kv2a, Kv2b, m2s, m2ss, FspAug,
                                   Hb, ln2g, ln2b, W2vb, l2b, Fvp);
  k_prep<<<Bn, 256, 0, stream>>>(Fvp, Fvn, FspAug, Gb);
  k_scores<<<dim3(Bn, 8), 256, 0, stream>>>(FtB, FspAug, Sc);
  k_attn4<<<4096 + Ln, 64, 0, stream>>>(Fs, Sc, Gb, invFt, invPr, gp, gnm,
                                        label, Fvn, proto, out);
}

// Round 21
// 141.533 us; speedup vs baseline: 1.1685x; 1.0336x over previous
//
#include <hip/hip_runtime.h>

// ---------------------------------------------------------------------------
// DPM_Block — Round 21: exact revert to R18 (best measured: 141.2us).
// R20's k_scores (256,4) bound removed (was +5us vs R18). No other changes.
// ---------------------------------------------------------------------------

#define Bn 128
#define Sn 49
#define Cn 512
#define Ln 1000
#define BL (Bn*Ln)
#define VQ 2048

typedef unsigned short u16;
typedef unsigned int u32;

using bfrag = __attribute__((ext_vector_type(8))) short;   // 8 bf16 (4 VGPR)
using ffrag = __attribute__((ext_vector_type(4))) float;   // 4 f32 acc

typedef const __attribute__((address_space(1))) u32 gq_t;
typedef __attribute__((address_space(3))) u32 lq_t;

__device__ __forceinline__ float bf2f(u16 u){ return __uint_as_float(((u32)u) << 16); }
__device__ __forceinline__ float bflo(u32 u){ return __uint_as_float(u << 16); }
__device__ __forceinline__ float bfhi(u32 u){ return __uint_as_float(u & 0xffff0000u); }
__device__ __forceinline__ u16 f2bf(float f){
  u32 x = __float_as_uint(f);
  u32 r = x + 0x7fffu + ((x >> 16) & 1u);   // RNE
  return (u16)(r >> 16);
}
__device__ __forceinline__ u16 f2h(float f){
  _Float16 h = (_Float16)f; return *(u16*)&h;
}
__device__ __forceinline__ float h2f(u16 u){
  _Float16 h = *(_Float16*)&u; return (float)h;
}

template<int BF>
__device__ __forceinline__ float ldin(const void* p, int i){
  if (BF) return bf2f(((const u16*)p)[i]);
  return ((const float*)p)[i];
}

template<int BF>
__device__ __forceinline__ void ld8(const void* p, int base, float* w){
  if (BF){
    uint4 u = *(const uint4*)((const u16*)p + base);
    w[0]=bflo(u.x); w[1]=bfhi(u.x); w[2]=bflo(u.y); w[3]=bfhi(u.y);
    w[4]=bflo(u.z); w[5]=bfhi(u.z); w[6]=bflo(u.w); w[7]=bfhi(u.w);
  } else {
    float4 a = *(const float4*)((const float*)p + base);
    float4 b = *(const float4*)((const float*)p + base + 4);
    w[0]=a.x; w[1]=a.y; w[2]=a.z; w[3]=a.w;
    w[4]=b.x; w[5]=b.y; w[6]=b.z; w[7]=b.w;
  }
}

__device__ __forceinline__ uint4 pack8(const float* w){
  uint4 v;
  v.x = (u32)f2bf(w[0]) | ((u32)f2bf(w[1])<<16);
  v.y = (u32)f2bf(w[2]) | ((u32)f2bf(w[3])<<16);
  v.z = (u32)f2bf(w[4]) | ((u32)f2bf(w[5])<<16);
  v.w = (u32)f2bf(w[6]) | ((u32)f2bf(w[7])<<16);
  return v;
}

__device__ __forceinline__ float ld_gamma(const void* p, int BF){
  float fb = bf2f(((const u16*)p)[0]);
  float ff = ((const float*)p)[0];
  bool pb = (fb > 0.05f && fb < 1.5f);
  bool pf = (ff > 0.05f && ff < 1.5f);
  if (pb && !pf) return fb;
  if (pf && !pb) return ff;
  return BF ? fb : ff;
}

// ---- inline dtype detector ----
__device__ __forceinline__ int detect_bf(const void* Fs){
  int lane = threadIdx.x & 63;
  uint4 v = ((const uint4*)Fs)[lane];
  u32 w[4] = {v.x, v.y, v.z, v.w};
  int c = 0;
  #pragma unroll
  for (int j = 0; j < 4; ++j){
    int e = (w[j] >> 7) & 0xff;
    c += (e >= 0x70 && e <= 0x8f);
  }
  #pragma unroll
  for (int m = 32; m; m >>= 1) c += __shfl_xor(c, m);
  return c >= 200;
}

__device__ __forceinline__ float2 block_red2(float a, float b, float* scratch){
  __syncthreads();
  #pragma unroll
  for (int off = 32; off; off >>= 1){ a += __shfl_xor(a, off); b += __shfl_xor(b, off); }
  int lane = threadIdx.x & 63, wid = threadIdx.x >> 6;
  if (lane == 0){ scratch[wid] = a; scratch[wid + 4] = b; }
  __syncthreads();
  return make_float2(scratch[0] + scratch[1] + scratch[2] + scratch[3],
                     scratch[4] + scratch[5] + scratch[6] + scratch[7]);
}

// -------------------- bodies --------------------
template<int BF>
__device__ void gn1_body(int b, const void* Fs, float* m1, float* rs1, u16* Fsb,
                         float* m2s, float* m2ss, float* red){
  int tid = threadIdx.x;
  if (tid == 0){ m2s[b] = 0.f; m2ss[b] = 0.f; }
  float s = 0.f, ss = 0.f;
  for (int i = tid; i < Sn*Cn/8; i += 256){
    float w[8]; ld8<BF>(Fs, b*Sn*Cn + i*8, w);
    #pragma unroll
    for (int j = 0; j < 8; ++j){ s += w[j]; ss += w[j]*w[j]; }
    *(uint4*)(Fsb + (size_t)b*Sn*Cn + i*8) = pack8(w);
  }
  float2 r = block_red2(s, ss, red);
  if (tid == 0){
    float m = r.x * (1.f/(Sn*Cn));
    float v = r.y * (1.f/(Sn*Cn)) - m*m;
    m1[b] = m; rs1[b] = rsqrtf(v + 1e-5f);
  }
}

template<int BF>
__device__ void wk_body(int blk, const void* W1, const void* W2, const void* W3,
    const void* W4, const void* g1, const void* g2, const void* bb1, const void* bb2,
    const void* bias1, const void* bias2,
    u16* D1, u16* D2, u16* D3, u16* D4,
    float* K1a, float* K1b, float* K2a, float* K2b){
  if (blk < 512){
    int i = blk*256 + threadIdx.x;
    int sel = i >> 15;
    const void* src = (sel==0) ? W1 : (sel==1) ? W2 : (sel==2) ? W3 : W4;
    u16* dst = (sel==0) ? D1 : (sel==1) ? D2 : (sel==2) ? D3 : D4;
    int off = (i & 32767)*8;
    float w[8]; ld8<BF>(src, off, w);
    if (sel <= 1){
      const void* g = sel ? g2 : g1;
      int c0 = off & 511;
      #pragma unroll
      for (int j = 0; j < 8; ++j) w[j] *= ldin<BF>(g, c0 + j);
    }
    *(uint4*)(dst + off) = pack8(w);
  } else {
    int idx = (blk - 512)*4 + (threadIdx.x >> 6);
    int lane = threadIdx.x & 63;
    int o = idx & 511, sel = idx >> 9;
    const void* W  = sel ? W2 : W1;
    const void* g  = sel ? g2 : g1;
    const void* bb = sel ? bb2 : bb1;
    const void* bi = sel ? bias2 : bias1;
    float* Ka = sel ? K2a : K1a;
    float* Kb = sel ? K2b : K1b;
    float w[8], gv[8], bv[8];
    ld8<BF>(W, o*Cn + lane*8, w);
    ld8<BF>(g, lane*8, gv);
    ld8<BF>(bb, lane*8, bv);
    float a = 0.f, b2 = 0.f;
    #pragma unroll
    for (int j = 0; j < 8; ++j){ a += w[j]*bv[j]; b2 += w[j]*gv[j]; }
    #pragma unroll
    for (int m = 32; m; m >>= 1){ a += __shfl_xor(a, m); b2 += __shfl_xor(b2, m); }
    if (lane == 0){ Ka[o] = a + ldin<BF>(bi, o); Kb[o] = b2; }
  }
}

template<int BF>
__device__ void protonorm_body(int l, const void* Ft, const void* Pr,
                               float* invFt, float* invPr,
                               u16* FtB, u16* PrB, float* red){
  int tid = threadIdx.x;
  if (l >= Ln){
    FtB[(size_t)l*512 + tid] = 0; FtB[(size_t)l*512 + tid + 256] = 0;
    PrB[(size_t)l*512 + tid] = 0; PrB[(size_t)l*512 + tid + 256] = 0;
    return;
  }
  float a0 = ldin<BF>(Ft, l*Cn + tid), a1 = ldin<BF>(Ft, l*Cn + tid + 256);
  float p0 = ldin<BF>(Pr, l*Cn + tid), p1 = ldin<BF>(Pr, l*Cn + tid + 256);
  FtB[(size_t)l*512 + tid] = f2bf(a0); FtB[(size_t)l*512 + tid + 256] = f2bf(a1);
  PrB[(size_t)l*512 + tid] = f2bf(p0); PrB[(size_t)l*512 + tid + 256] = f2bf(p1);
  float2 r = block_red2(a0*a0 + a1*a1, p0*p0 + p1*p1, red);
  if (tid == 0){
    invFt[l] = 1.f / fmaxf(sqrtf(r.x), 1e-12f);
    invPr[l] = 1.f / fmaxf(sqrtf(r.y), 1e-12f);
  }
}

// ---- launch 1: [0,512) wconv, [512,768) kvec, [768,1792) protonorm,
//      [1792,1920) gn1 ----
__global__ __launch_bounds__(256) void k_gn1wk(const void* Fs,
    const void* W1, const void* W2, const void* W3, const void* W4,
    const void* g1, const void* g2, const void* bb1, const void* bb2,
    const void* bias1, const void* bias2,
    u16* D1, u16* D2, u16* D3, u16* D4,
    float* K1a, float* K1b, float* K2a, float* K2b,
    const void* Ft, const void* Pr, float* invFt, float* invPr, u16* FtB, u16* PrB,
    float* m1, float* rs1, u16* Fsb, float* m2s, float* m2ss){
  __shared__ float red[8];
  int bf = detect_bf(Fs);
  int blk = blockIdx.x;
  if (blk < 768){
    if (bf) wk_body<1>(blk, W1, W2, W3, W4, g1, g2, bb1, bb2, bias1, bias2,
                       D1, D2, D3, D4, K1a, K1b, K2a, K2b);
    else    wk_body<0>(blk, W1, W2, W3, W4, g1, g2, bb1, bb2, bias1, bias2,
                       D1, D2, D3, D4, K1a, K1b, K2a, K2b);
  } else if (blk < 1792){
    int l = blk - 768;
    if (bf) protonorm_body<1>(l, Ft, Pr, invFt, invPr, FtB, PrB, red);
    else    protonorm_body<0>(l, Ft, Pr, invFt, invPr, FtB, PrB, red);
  } else {
    int b = blk - 1792;
    if (bf) gn1_body<1>(b, Fs, m1, rs1, Fsb, m2s, m2ss, red);
    else    gn1_body<0>(b, Fs, m1, rs1, Fsb, m2s, m2ss, red);
  }
}

// ------- MFMA conv body (GN folded), b/o0 passed in (256 threads) -----------
template<int C1>
__device__ void convm_body(int b, int o0,
    const u16* __restrict__ src, const u16* __restrict__ Wb,
    const float* __restrict__ Ka, const float* __restrict__ Kb,
    float mean, float rs, u16* dst, u16* Bs, float* red,
    float* m2s, float* m2ss){
  int tid = threadIdx.x;
  int lane = tid & 63, wid = tid >> 6, lq = lane & 15, g4 = lane >> 4;
  for (int idx = tid; idx < 15*64; idx += 256){
    int r = 49 + (idx >> 6), j = idx & 63;
    *(uint4*)(Bs + (r<<9) + (j<<3)) = (uint4){0,0,0,0};
  }
  #pragma unroll
  for (int is = 0; is < 13; ++is){
    int r = is*4 + wid;
    if (r < Sn){
      const u16* gsrc = src + (size_t)(b*Sn + r)*Cn + ((lane ^ (r & 7)) << 3);
      u16* ldst = Bs + (r << 9);
      __builtin_amdgcn_global_load_lds((gq_t*)gsrc, (lq_t*)ldst, 16, 0, 0);
    }
  }
  __syncthreads();
  float gs = 0.f, gss = 0.f;
  #pragma unroll
  for (int ot = 0; ot < 2; ++ot){
    int oA = o0 + wid*32 + ot*16;
    bfrag af[16];
    #pragma unroll
    for (int kb = 0; kb < 16; ++kb)
      af[kb] = *(const bfrag*)(Wb + (size_t)(oA + lq)*Cn + kb*32 + g4*8);
    ffrag acc[4];
    #pragma unroll
    for (int st = 0; st < 4; ++st) acc[st] = (ffrag){0.f,0.f,0.f,0.f};
    #pragma unroll
    for (int st = 0; st < 4; ++st){
      int srow = st*16 + lq;
      #pragma unroll
      for (int kb = 0; kb < 16; ++kb){
        bfrag bf_ = *(const bfrag*)(Bs + (srow<<9) + (((kb*4+g4) ^ (srow&7))<<3));
        acc[st] = __builtin_amdgcn_mfma_f32_16x16x32_bf16(af[kb], bf_, acc[st], 0,0,0);
      }
    }
    int ob = oA + g4*4;
    float cst[4];
    #pragma unroll
    for (int r = 0; r < 4; ++r) cst[r] = Ka[ob + r] - mean*rs*Kb[ob + r];
    #pragma unroll
    for (int st = 0; st < 4; ++st){
      int s = st*16 + lq;
      u16 pk[4];
      #pragma unroll
      for (int r = 0; r < 4; ++r){
        float val = rs*acc[st][r] + cst[r];
        if (C1){
          val = fmaxf(val, 0.f);
          if (s < Sn){ gs += val; gss += val*val; }
        }
        pk[r] = f2bf(val);
      }
      if (C1){
        if (s < Sn) *(uint2*)(dst + ((size_t)(b*Sn + s)<<9) + ob) = *(const uint2*)pk;
      } else {
        if (s >= Sn){ pk[0]=0; pk[1]=0; pk[2]=0; pk[3]=0; }
        *(uint2*)(dst + ((size_t)(b*64 + s)<<9) + ob) = *(const uint2*)pk;
      }
    }
  }
  if (C1){
    float2 r2 = block_red2(gs, gss, red);
    if (tid == 0){
      atomicAdd(&m2s[b], r2.x);
      atomicAdd(&m2ss[b], r2.y);
    }
  }
}

// ------------- vector MLP body, o0 passed in (256 threads) ------------------
template<int BF, int SBF, int PH>
__device__ void vg_body(int o0, const void* src, const void* lng, const void* lnb,
    const u16* __restrict__ Wv, const void* bias, void* outp,
    u16* Bt, u16* Ach, float* mrow, float* rrow, float* Gc, float* Bc2){
  int tid = threadIdx.x, lane = tid & 63, wid = tid >> 6;
  int lq = lane & 15, g4 = lane >> 4;
  for (int c = tid; c < Cn; c += 256){ Gc[c] = ldin<BF>(lng, c); Bc2[c] = ldin<BF>(lnb, c); }
  {
    int r = tid >> 1, h = tid & 1;
    float s = 0.f, ss = 0.f;
    #pragma unroll 4
    for (int k = 0; k < 32; ++k){
      float w[8]; ld8<SBF>(src, r*Cn + h*256 + k*8, w);
      #pragma unroll
      for (int j = 0; j < 8; ++j){ s += w[j]; ss += w[j]*w[j]; }
    }
    s += __shfl_xor(s, 1); ss += __shfl_xor(ss, 1);
    if (h == 0){
      float m = s * (1.f/Cn);
      mrow[r] = m; rrow[r] = rsqrtf(ss * (1.f/Cn) - m*m + 1e-5f);
    }
  }
  for (int idx = tid; idx < 16*64; idx += 256){
    int row = idx >> 6, j = idx & 63;
    uint4 v = *(const uint4*)(Wv + (size_t)(o0 + row)*Cn + j*8);
    *(uint4*)(Bt + (row<<9) + ((j ^ (row&7))<<3)) = v;
  }
  __syncthreads();
  ffrag acc[2];
  acc[0] = (ffrag){0.f,0.f,0.f,0.f};
  acc[1] = (ffrag){0.f,0.f,0.f,0.f};
  for (int kc = 0; kc < 4; ++kc){
    if (kc) __syncthreads();
    for (int idx = tid; idx < 128*16; idx += 256){
      int row = idx >> 4, j = idx & 15;
      int c = kc*128 + j*8;
      float w[8]; ld8<SBF>(src, row*Cn + c, w);
      float mu = mrow[row], rsd = rrow[row];
      #pragma unroll
      for (int k2 = 0; k2 < 8; ++k2) w[k2] = (w[k2]-mu)*rsd*Gc[c+k2] + Bc2[c+k2];
      *(uint4*)(Ach + (row<<7) + ((j ^ (row&15))<<3)) = pack8(w);
    }
    __syncthreads();
    #pragma unroll
    for (int mt2 = 0; mt2 < 2; ++mt2){
      int arow = (wid*2 + mt2)*16 + lq;
      #pragma unroll
      for (int kb = 0; kb < 4; ++kb){
        bfrag af = *(const bfrag*)(Ach + (arow<<7) + (((kb*4+g4) ^ (arow&15))<<3));
        bfrag bf_ = *(const bfrag*)(Bt + (lq<<9) + (((kc*16 + kb*4 + g4) ^ (lq&7))<<3));
        acc[mt2] = __builtin_amdgcn_mfma_f32_16x16x32_bf16(af, bf_, acc[mt2], 0,0,0);
      }
    }
  }
  float bval = ldin<BF>(bias, o0 + lq);
  #pragma unroll
  for (int mt2 = 0; mt2 < 2; ++mt2){
    #pragma unroll
    for (int r = 0; r < 4; ++r){
      int brow = wid*32 + mt2*16 + g4*4 + r;
      float val = acc[mt2][r] + bval;
      if (PH == 1){
        ((u16*)outp)[brow*Cn + o0 + lq] = f2bf(fmaxf(val, 0.f));
      } else {
        ((float*)outp)[brow*Cn + o0 + lq] = val;
      }
    }
  }
}

// LDS union: conv = 64KB Bs + 32B red; vg = 53KB carved
#define CV_SHARED __shared__ __align__(16) char smu[65568];

// ---- launch 2: vg1 (blocks 0..31) + conv1m (32..543) ----
__global__ __launch_bounds__(256, 2) void k_c1vg1(const void* Fs,
    const u16* Fsb, const u16* W1b, const float* Ka, const float* Kb,
    const float* m1, const float* rs1, u16* H1t, float* m2s, float* m2ss,
    const void* Fv, const void* ln1g, const void* ln1b,
    const u16* W1vb, const void* l1b, u16* Hb){
  CV_SHARED
  int blk = blockIdx.x;
  if (blk >= 32){
    u16* Bs = (u16*)smu;
    float* red = (float*)(smu + 65536);
    int cb = blk - 32;
    int b = cb >> 2, o0 = (cb & 3)*128;
    convm_body<1>(b, o0, Fsb, W1b, Ka, Kb, m1[b], rs1[b], H1t, Bs, red, m2s, m2ss);
  } else {
    u16* Bt = (u16*)smu;
    u16* Ach = (u16*)(smu + 16384);
    float* mrow = (float*)(smu + 49152);
    float* rrow = (float*)(smu + 49664);
    float* Gc = (float*)(smu + 50176);
    float* Bc2 = (float*)(smu + 52224);
    int o0 = blk*16;
    if (detect_bf(Fs)) vg_body<1,1,1>(o0, Fv, ln1g, ln1b, W1vb, l1b, Hb, Bt, Ach, mrow, rrow, Gc, Bc2);
    else               vg_body<0,0,1>(o0, Fv, ln1g, ln1b, W1vb, l1b, Hb, Bt, Ach, mrow, rrow, Gc, Bc2);
  }
}

// ---- launch 3: vg2 (blocks 0..31) + conv2m (32..543) ----
__global__ __launch_bounds__(256, 2) void k_c2vg2(const void* Fs,
    const u16* H1t, const u16* W2b, const float* Ka, const float* Kb,
    const float* m2s, const float* m2ss, u16* FspAug,
    const u16* Hb, const void* ln2g, const void* ln2b,
    const u16* W2vb, const void* l2b, float* Y2){
  CV_SHARED
  int blk = blockIdx.x;
  if (blk >= 32){
    u16* Bs = (u16*)smu;
    int cb = blk - 32;
    int b = cb >> 2, o0 = (cb & 3)*128;
    float sum = m2s[b], ssum = m2ss[b];
    float mean = sum * (1.f/(Sn*Cn));
    float var  = ssum * (1.f/(Sn*Cn)) - mean*mean;
    float rs = rsqrtf(var + 1e-5f);
    convm_body<0>(b, o0, H1t, W2b, Ka, Kb, mean, rs, FspAug, Bs,
                  (float*)nullptr, (float*)nullptr, (float*)nullptr);
  } else {
    u16* Bt = (u16*)smu;
    u16* Ach = (u16*)(smu + 16384);
    float* mrow = (float*)(smu + 49152);
    float* rrow = (float*)(smu + 49664);
    float* Gc = (float*)(smu + 50176);
    float* Bc2 = (float*)(smu + 52224);
    int o0 = blk*16;
    if (detect_bf(Fs)) vg_body<1,1,2>(o0, Hb, ln2g, ln2b, W2vb, l2b, Y2, Bt, Ach, mrow, rrow, Gc, Bc2);
    else               vg_body<0,1,2>(o0, Hb, ln2g, ln2b, W2vb, l2b, Y2, Bt, Ach, mrow, rrow, Gc, Bc2);
  }
}

// --- k_prep: Fvn = l2norm(Fvp) (fused); aug rows 56/57; G = Aug·Aug^T -------
__global__ __launch_bounds__(256) void k_prep(const float* __restrict__ Fvp,
    float* __restrict__ Fvn, u16* __restrict__ FspAug, u16* __restrict__ Gb){
  __shared__ u16 xa[64*512];
  __shared__ float red[8];
  __shared__ float fvrow[512];
  int b = blockIdx.x, tid = threadIdx.x;
  int lane = tid & 63, wid = tid >> 6, lq = lane & 15, g4 = lane >> 4;
  float x0 = Fvp[b*Cn + tid], x1 = Fvp[b*Cn + tid + 256];
  float2 rr = block_red2(x0*x0 + x1*x1, 0.f, red);
  float inv = 1.f / fmaxf(sqrtf(rr.x), 1e-12f);
  fvrow[tid] = x0*inv; fvrow[tid + 256] = x1*inv;
  Fvn[b*Cn + tid] = x0*inv; Fvn[b*Cn + tid + 256] = x1*inv;
  __syncthreads();
  for (int idx = tid; idx < 64*64; idx += 256){
    int s = idx >> 6, j = idx & 63;
    uint4 v;
    if (s == 56 || s == 57){
      float w[8];
      if (s == 56){
        const float* src = Fvp + b*Cn + j*8;
        #pragma unroll
        for (int k = 0; k < 8; ++k) w[k] = src[k];
      } else {
        #pragma unroll
        for (int k = 0; k < 8; ++k) w[k] = fvrow[j*8 + k];
      }
      v = pack8(w);
      *(uint4*)(FspAug + ((size_t)(b*64 + s))*512 + j*8) = v;
    } else {
      v = *(const uint4*)(FspAug + ((size_t)(b*64 + s))*512 + j*8);
    }
    *(uint4*)(xa + s*512 + ((j ^ (s&7)) << 3)) = v;
  }
  __syncthreads();
  int mt = wid;
  for (int nt = 0; nt < 4; ++nt){
    ffrag acc = {0.f, 0.f, 0.f, 0.f};
    #pragma unroll
    for (int kb = 0; kb < 16; ++kb){
      int j = kb*4 + g4;
      int rowa = mt*16 + lq, rowb = nt*16 + lq;
      bfrag af  = *(const bfrag*)(xa + rowa*512 + ((j ^ (rowa&7)) << 3));
      bfrag bf_ = *(const bfrag*)(xa + rowb*512 + ((j ^ (rowb&7)) << 3));
      acc = __builtin_amdgcn_mfma_f32_16x16x32_bf16(af, bf_, acc, 0, 0, 0);
    }
    #pragma unroll
    for (int r = 0; r < 4; ++r)
      Gb[(size_t)b*4096 + (mt*16 + g4*4 + r)*64 + nt*16 + lq] = f2bf(acc[r]);
  }
}

// ------- K1: scores GEMM -> f16; async staging; grid (Bn, 8) ---------------
__global__ __launch_bounds__(256, 3) void k_scores(const u16* __restrict__ LB,
    const u16* __restrict__ FspAug, u16* __restrict__ Sc){
  __shared__ u16 At[64*256];   // 32768 B
  int b = blockIdx.x, lg = blockIdx.y;
  int tid = threadIdx.x, lane = tid & 63, wid = tid >> 6;
  int lq = lane & 15, g4 = lane >> 4;
  int l32 = lane & 31, rh = lane >> 5;
  bfrag breg[16];
  {
    const u16* fa = FspAug + ((size_t)(b*64 + wid*16 + lq))*512 + g4*8;
    #pragma unroll
    for (int kb = 0; kb < 16; ++kb) breg[kb] = *(const bfrag*)(fa + kb*32);
  }
  for (int chunk = 0; chunk < 4; ++chunk){
    int qi = lg*4 + chunk;
    ffrag acc[4];
    #pragma unroll
    for (int lt = 0; lt < 4; ++lt) acc[lt] = (ffrag){0.f,0.f,0.f,0.f};
    for (int kc = 0; kc < 2; ++kc){
      __syncthreads();   // guard At rewrite
      #pragma unroll
      for (int is = 0; is < 8; ++is){
        int r = (is*4 + wid)*2 + rh;
        const u16* gsrc = LB + (size_t)(qi*64 + r)*512 + kc*256 + ((l32 ^ (r & 7)) << 3);
        u16* ldst = At + ((is*4 + wid) << 9);
        __builtin_amdgcn_global_load_lds((gq_t*)gsrc, (lq_t*)ldst, 16, 0, 0);
      }
      __syncthreads();
      #pragma unroll
      for (int kb = 0; kb < 8; ++kb){
        #pragma unroll
        for (int lt = 0; lt < 4; ++lt){
          int row = lt*16 + lq;
          bfrag af = *(const bfrag*)(At + (row<<8) + (((kb*4+g4) ^ (row&7))<<3));
          acc[lt] = __builtin_amdgcn_mfma_f32_16x16x32_bf16(af, breg[kc*8+kb], acc[lt], 0,0,0);
        }
      }
    }
    #pragma unroll
    for (int lt = 0; lt < 4; ++lt){
      #pragma unroll
      for (int r = 0; r < 4; ++r){
        size_t row = (size_t)b*VQ + qi*64 + lt*16 + g4*4 + r;
        Sc[row*64 + wid*16 + lq] = f2h(acc[lt][r]);
      }
    }
  }
}

// -- K2: row-per-lane softmax + gram epilogue; blocks >= 4096 do proto update
__global__ __launch_bounds__(64) void k_attn4(const void* Fs,
    const u16* __restrict__ Sc, const u16* __restrict__ Gb,
    const float* __restrict__ invFt, const float* __restrict__ invPr,
    const void* gp_, const void* gn_,
    const int* __restrict__ label, const float* __restrict__ Fvn,
    const void* Pr, float* __restrict__ out){
  __shared__ u16 a1t[64*72];
  __shared__ float agab[64], wvb[64];
  __shared__ int lab[128];
  int bid = blockIdx.x;
  int bf = detect_bf(Fs);
  int lane = threadIdx.x;
  if (bid >= 4096){
    int l = bid - 4096;
    lab[lane] = label[lane]; lab[lane + 64] = label[lane + 64];
    __syncthreads();
    float sum[8] = {0.f,0.f,0.f,0.f,0.f,0.f,0.f,0.f};
    int cnt = 0;
    for (int i = 0; i < Bn; ++i){
      if (lab[i] == l){
        cnt++;
        const float4* v = (const float4*)(Fvn + i*Cn + lane*8);
        float4 a = v[0], c = v[1];
        sum[0]+=a.x; sum[1]+=a.y; sum[2]+=a.z; sum[3]+=a.w;
        sum[4]+=c.x; sum[5]+=c.y; sum[6]+=c.z; sum[7]+=c.w;
      }
    }
    int base = l*Cn + lane*8;
    float* dst = out + 3*BL + base;
    if (cnt > 0){
      float sc = 0.01f / fmaxf((float)cnt, 1e-8f);
      #pragma unroll
      for (int j = 0; j < 8; ++j)
        dst[j] = 0.99f*(bf ? ldin<1>(Pr, base+j) : ldin<0>(Pr, base+j)) + sum[j]*sc;
    } else {
      #pragma unroll
      for (int j = 0; j < 8; ++j)
        dst[j] = bf ? ldin<1>(Pr, base+j) : ldin<0>(Pr, base+j);
    }
    return;
  }
  int qi = bid & 31, b = bid >> 5;
  int lq = lane & 15, g4 = lane >> 4;

  u32 w32[32];
  {
    const uint4* rp = (const uint4*)(Sc + ((size_t)b*VQ + qi*64 + lane)*64);
    #pragma unroll
    for (int i = 0; i < 8; ++i){
      uint4 v = rp[i];
      w32[i*4+0] = v.x; w32[i*4+1] = v.y; w32[i*4+2] = v.z; w32[i*4+3] = v.w;
    }
  }
  #define XS(s) h2f((u16)(((s)&1) ? (w32[(s)>>1] >> 16) : (w32[(s)>>1] & 0xffffu)))
  float mx = -1e30f;
  #pragma unroll
  for (int s = 0; s < Sn; ++s) mx = fmaxf(mx, XS(s));
  float raw56 = XS(56), raw57 = XS(57);
  float sm = 0.f, dx = 0.f;
  #pragma unroll
  for (int u = 0; u < 7; ++u){
    u32 pw[4];
    #pragma unroll
    for (int i = 0; i < 4; ++i){
      u32 w2 = 0;
      #pragma unroll
      for (int h = 0; h < 2; ++h){
        int s = u*8 + i*2 + h;
        float x = XS(s);
        float e = (s < Sn) ? __expf(x - mx) : 0.f;
        sm += e; dx += e * x;
        w2 |= ((u32)f2bf(e)) << (16*h);
      }
      pw[i] = w2;
    }
    *(uint4*)(a1t + lane*72 + u*8) = make_uint4(pw[0], pw[1], pw[2], pw[3]);
  }
  #undef XS

  const u16* gbase = Gb + (size_t)b*4096;
  #pragma unroll
  for (int qt = 0; qt < 4; ++qt){
    float pr[4] = {0.f, 0.f, 0.f, 0.f};
    float wvl[4] = {0.f, 0.f, 0.f, 0.f};
    #pragma unroll
    for (int nt = 0; nt < 4; ++nt){
      ffrag acc = {0.f, 0.f, 0.f, 0.f};
      #pragma unroll
      for (int kb2 = 0; kb2 < 2; ++kb2){
        bfrag af;
        if (kb2 == 1 && g4 == 3) af = (bfrag){0,0,0,0,0,0,0,0};
        else af = *(const bfrag*)(a1t + (qt*16 + lq)*72 + (g4 + 4*kb2)*8);
        bfrag bg = *(const bfrag*)(gbase + (nt*16 + lq)*64 + kb2*32 + g4*8);
        acc = __builtin_amdgcn_mfma_f32_16x16x32_bf16(af, bg, acc, 0, 0, 0);
      }
      int sp = nt*16 + lq;
      #pragma unroll
      for (int r = 0; r < 4; ++r){
        int q = qt*16 + g4*4 + r;
        float av = (sp < 56) ? bf2f(a1t[q*72 + sp]) : 0.f;
        pr[r] += av * acc[r];
        if (nt == 3 && lq == 8) wvl[r] = acc[r];
      }
    }
    #pragma unroll
    for (int m = 1; m <= 8; m <<= 1){
      #pragma unroll
      for (int r = 0; r < 4; ++r) pr[r] += __shfl_xor(pr[r], m);
    }
    if (lq == 0){
      #pragma unroll
      for (int r = 0; r < 4; ++r) agab[qt*16 + g4*4 + r] = pr[r];
    }
    if (lq == 8){
      #pragma unroll
      for (int r = 0; r < 4; ++r) wvb[qt*16 + g4*4 + r] = wvl[r];
    }
  }

  int vq = qi*64 + lane;
  int path = vq >> 10, l = vq & 1023;
  if (l < Ln){
    float gp = ld_gamma(gp_, bf), gn = ld_gamma(gn_, bf);
    float fvpSq = bf2f(gbase[56*64 + 56]);
    float inv_sm = 1.f / sm;
    float aGa = agab[lane] * inv_sm * inv_sm;
    float wv  = wvb[lane] * inv_sm;
    float gam = path ? gn : gp;
    float ns  = gam*gam*aGa + 2.f*gam*wv + fvpSq;
    float dt  = gam*(dx*inv_sm) + raw56;
    float invx = (path ? invPr : invFt)[l];
    float lg2 = dt * invx / fmaxf(sqrtf(ns), 1e-12f);
    if (path == 0){
      out[(size_t)b*Ln + l]              = raw57 * invx;
      out[(size_t)BL + (size_t)b*Ln + l] = lg2;
    } else {
      out[(size_t)2*BL + (size_t)b*Ln + l] = lg2;
    }
  }
}

// ---------------------------------------------------------------------------
extern "C" void kernel_launch(void* const* d_in, const int* in_sizes, int n_in,
                              void* d_out, int out_size, void* d_ws, size_t ws_size,
                              hipStream_t stream){
  (void)in_sizes; (void)n_in; (void)out_size; (void)ws_size;
  const void* Fs    = d_in[0];
  const void* Ft    = d_in[1];
  const void* Fv    = d_in[2];
  const int*  label = (const int*)d_in[3];
  const void* gn1g  = d_in[4];
  const void* gn1b  = d_in[5];
  const void* c1w   = d_in[6];
  const void* c1b   = d_in[7];
  const void* gn2g  = d_in[8];
  const void* gn2b  = d_in[9];
  const void* c2w   = d_in[10];
  const void* c2b   = d_in[11];
  const void* ln1g  = d_in[12];
  const void* ln1b  = d_in[13];
  const void* l1w   = d_in[14];
  const void* l1b   = d_in[15];
  const void* ln2g  = d_in[16];
  const void* ln2b  = d_in[17];
  const void* l2w   = d_in[18];
  const void* l2b   = d_in[19];
  const void* gp    = d_in[20];
  const void* gnm   = d_in[21];
  const void* proto = d_in[22];
  float* out = (float*)d_out;
  float* ws  = (float*)d_ws;

  float* m1    = ws + 0;
  float* rs1   = ws + 128;
  float* m2s   = ws + 256;
  float* m2ss  = ws + 384;
  float* invFt = ws + 512;
  float* invPr = ws + 1536;
  u16*   H1t   = (u16*)(ws + 4096);                 // B*49*512 bf16
  float* Fvp   = ws + 4096 + (size_t)Bn*Sn*Cn/2;    // B*C f32
  float* Fvn   = Fvp + Bn*Cn;
  u16*   FspAug= (u16*)(Fvn + Bn*Cn);               // B*64*512 bf16
  u16*   FtB   = FspAug + (size_t)Bn*64*512;        // 1024*512 bf16 (PrB follows)
  u16*   PrB   = FtB + (size_t)1024*512;
  u16*   Gb    = PrB + (size_t)1024*512;            // B*64*64 bf16
  u16*   W1b   = Gb + (size_t)Bn*4096;              // 512*512 bf16 x4
  u16*   W2b   = W1b + (size_t)512*512;
  u16*   W1vb  = W2b + (size_t)512*512;
  u16*   W2vb  = W1vb + (size_t)512*512;
  u16*   Hb    = W2vb + (size_t)512*512;            // 128*512 bf16
  u16*   Fsb   = Hb + (size_t)Bn*Cn;                // B*49*512 bf16
  float* Kv1a  = (float*)(Fsb + (size_t)Bn*Sn*Cn);  // 4 x 512 f32
  float* Kv1b  = Kv1a + 512;
  float* Kv2a  = Kv1b + 512;
  float* Kv2b  = Kv2a + 512;
  u16*   Sc    = (u16*)(Kv2b + 512);                // B*2048*64 f16 (33.5MB)

  k_gn1wk<<<1920, 256, 0, stream>>>(Fs, c1w, c2w, l1w, l2w, gn1g, gn2g,
                                    gn1b, gn2b, c1b, c2b,
                                    W1b, W2b, W1vb, W2vb, Kv1a, Kv1b, Kv2a, Kv2b,
                                    Ft, proto, invFt, invPr, FtB, PrB,
                                    m1, rs1, Fsb, m2s, m2ss);
  k_c1vg1<<<544, 256, 0, stream>>>(Fs, Fsb, W1b, Kv1a, Kv1b, m1, rs1, H1t, m2s, m2ss,
                                   Fv, ln1g, ln1b, W1vb, l1b, Hb);
  k_c2vg2<<<544, 256, 0, stream>>>(Fs, H1t, W2b, Kv2a, Kv2b, m2s, m2ss, FspAug,
                                   Hb, ln2g, ln2b, W2vb, l2b, Fvp);
  k_prep<<<Bn, 256, 0, stream>>>(Fvp, Fvn, FspAug, Gb);
  k_scores<<<dim3(Bn, 8), 256, 0, stream>>>(FtB, FspAug, Sc);
  k_attn4<<<4096 + Ln, 64, 0, stream>>>(Fs, Sc, Gb, invFt, invPr, gp, gnm,
                                        label, Fvn, proto, out);
}

// Round 22
// 136.609 us; speedup vs baseline: 1.2106x; 1.0360x over previous
//
#include <hip/hip_runtime.h>

// ---------------------------------------------------------------------------
// DPM_Block — Round 22: R21 base (141.5us) + 512-thread conv/vg with the
// CORRECTED bound (512,2): 2 blocks/CU x 8 waves = 16 waves/CU, VGPR cap 128
// (R19's (512,4) meant 4 blocks/CU -> cap 64 -> spill cliff).
// ---------------------------------------------------------------------------

#define Bn 128
#define Sn 49
#define Cn 512
#define Ln 1000
#define BL (Bn*Ln)
#define VQ 2048

typedef unsigned short u16;
typedef unsigned int u32;

using bfrag = __attribute__((ext_vector_type(8))) short;   // 8 bf16 (4 VGPR)
using ffrag = __attribute__((ext_vector_type(4))) float;   // 4 f32 acc

typedef const __attribute__((address_space(1))) u32 gq_t;
typedef __attribute__((address_space(3))) u32 lq_t;

__device__ __forceinline__ float bf2f(u16 u){ return __uint_as_float(((u32)u) << 16); }
__device__ __forceinline__ float bflo(u32 u){ return __uint_as_float(u << 16); }
__device__ __forceinline__ float bfhi(u32 u){ return __uint_as_float(u & 0xffff0000u); }
__device__ __forceinline__ u16 f2bf(float f){
  u32 x = __float_as_uint(f);
  u32 r = x + 0x7fffu + ((x >> 16) & 1u);   // RNE
  return (u16)(r >> 16);
}
__device__ __forceinline__ u16 f2h(float f){
  _Float16 h = (_Float16)f; return *(u16*)&h;
}
__device__ __forceinline__ float h2f(u16 u){
  _Float16 h = *(_Float16*)&u; return (float)h;
}

template<int BF>
__device__ __forceinline__ float ldin(const void* p, int i){
  if (BF) return bf2f(((const u16*)p)[i]);
  return ((const float*)p)[i];
}

template<int BF>
__device__ __forceinline__ void ld8(const void* p, int base, float* w){
  if (BF){
    uint4 u = *(const uint4*)((const u16*)p + base);
    w[0]=bflo(u.x); w[1]=bfhi(u.x); w[2]=bflo(u.y); w[3]=bfhi(u.y);
    w[4]=bflo(u.z); w[5]=bfhi(u.z); w[6]=bflo(u.w); w[7]=bfhi(u.w);
  } else {
    float4 a = *(const float4*)((const float*)p + base);
    float4 b = *(const float4*)((const float*)p + base + 4);
    w[0]=a.x; w[1]=a.y; w[2]=a.z; w[3]=a.w;
    w[4]=b.x; w[5]=b.y; w[6]=b.z; w[7]=b.w;
  }
}

__device__ __forceinline__ uint4 pack8(const float* w){
  uint4 v;
  v.x = (u32)f2bf(w[0]) | ((u32)f2bf(w[1])<<16);
  v.y = (u32)f2bf(w[2]) | ((u32)f2bf(w[3])<<16);
  v.z = (u32)f2bf(w[4]) | ((u32)f2bf(w[5])<<16);
  v.w = (u32)f2bf(w[6]) | ((u32)f2bf(w[7])<<16);
  return v;
}

__device__ __forceinline__ float ld_gamma(const void* p, int BF){
  float fb = bf2f(((const u16*)p)[0]);
  float ff = ((const float*)p)[0];
  bool pb = (fb > 0.05f && fb < 1.5f);
  bool pf = (ff > 0.05f && ff < 1.5f);
  if (pb && !pf) return fb;
  if (pf && !pb) return ff;
  return BF ? fb : ff;
}

// ---- inline dtype detector ----
__device__ __forceinline__ int detect_bf(const void* Fs){
  int lane = threadIdx.x & 63;
  uint4 v = ((const uint4*)Fs)[lane];
  u32 w[4] = {v.x, v.y, v.z, v.w};
  int c = 0;
  #pragma unroll
  for (int j = 0; j < 4; ++j){
    int e = (w[j] >> 7) & 0xff;
    c += (e >= 0x70 && e <= 0x8f);
  }
  #pragma unroll
  for (int m = 32; m; m >>= 1) c += __shfl_xor(c, m);
  return c >= 200;
}

// 256-thread block reduction
__device__ __forceinline__ float2 block_red2(float a, float b, float* scratch){
  __syncthreads();
  #pragma unroll
  for (int off = 32; off; off >>= 1){ a += __shfl_xor(a, off); b += __shfl_xor(b, off); }
  int lane = threadIdx.x & 63, wid = threadIdx.x >> 6;
  if (lane == 0){ scratch[wid] = a; scratch[wid + 4] = b; }
  __syncthreads();
  return make_float2(scratch[0] + scratch[1] + scratch[2] + scratch[3],
                     scratch[4] + scratch[5] + scratch[6] + scratch[7]);
}

// 512-thread block reduction (scratch 16 floats)
__device__ __forceinline__ float2 block_red2_512(float a, float b, float* scratch){
  __syncthreads();
  #pragma unroll
  for (int off = 32; off; off >>= 1){ a += __shfl_xor(a, off); b += __shfl_xor(b, off); }
  int lane = threadIdx.x & 63, wid = threadIdx.x >> 6;
  if (lane == 0){ scratch[wid] = a; scratch[wid + 8] = b; }
  __syncthreads();
  float ra = 0.f, rb = 0.f;
  #pragma unroll
  for (int i = 0; i < 8; ++i){ ra += scratch[i]; rb += scratch[i + 8]; }
  return make_float2(ra, rb);
}

// -------------------- bodies --------------------
template<int BF>
__device__ void gn1_body(int b, const void* Fs, float* m1, float* rs1, u16* Fsb,
                         float* m2s, float* m2ss, float* red){
  int tid = threadIdx.x;
  if (tid == 0){ m2s[b] = 0.f; m2ss[b] = 0.f; }
  float s = 0.f, ss = 0.f;
  for (int i = tid; i < Sn*Cn/8; i += 256){
    float w[8]; ld8<BF>(Fs, b*Sn*Cn + i*8, w);
    #pragma unroll
    for (int j = 0; j < 8; ++j){ s += w[j]; ss += w[j]*w[j]; }
    *(uint4*)(Fsb + (size_t)b*Sn*Cn + i*8) = pack8(w);
  }
  float2 r = block_red2(s, ss, red);
  if (tid == 0){
    float m = r.x * (1.f/(Sn*Cn));
    float v = r.y * (1.f/(Sn*Cn)) - m*m;
    m1[b] = m; rs1[b] = rsqrtf(v + 1e-5f);
  }
}

template<int BF>
__device__ void wk_body(int blk, const void* W1, const void* W2, const void* W3,
    const void* W4, const void* g1, const void* g2, const void* bb1, const void* bb2,
    const void* bias1, const void* bias2,
    u16* D1, u16* D2, u16* D3, u16* D4,
    float* K1a, float* K1b, float* K2a, float* K2b){
  if (blk < 512){
    int i = blk*256 + threadIdx.x;
    int sel = i >> 15;
    const void* src = (sel==0) ? W1 : (sel==1) ? W2 : (sel==2) ? W3 : W4;
    u16* dst = (sel==0) ? D1 : (sel==1) ? D2 : (sel==2) ? D3 : D4;
    int off = (i & 32767)*8;
    float w[8]; ld8<BF>(src, off, w);
    if (sel <= 1){
      const void* g = sel ? g2 : g1;
      int c0 = off & 511;
      #pragma unroll
      for (int j = 0; j < 8; ++j) w[j] *= ldin<BF>(g, c0 + j);
    }
    *(uint4*)(dst + off) = pack8(w);
  } else {
    int idx = (blk - 512)*4 + (threadIdx.x >> 6);
    int lane = threadIdx.x & 63;
    int o = idx & 511, sel = idx >> 9;
    const void* W  = sel ? W2 : W1;
    const void* g  = sel ? g2 : g1;
    const void* bb = sel ? bb2 : bb1;
    const void* bi = sel ? bias2 : bias1;
    float* Ka = sel ? K2a : K1a;
    float* Kb = sel ? K2b : K1b;
    float w[8], gv[8], bv[8];
    ld8<BF>(W, o*Cn + lane*8, w);
    ld8<BF>(g, lane*8, gv);
    ld8<BF>(bb, lane*8, bv);
    float a = 0.f, b2 = 0.f;
    #pragma unroll
    for (int j = 0; j < 8; ++j){ a += w[j]*bv[j]; b2 += w[j]*gv[j]; }
    #pragma unroll
    for (int m = 32; m; m >>= 1){ a += __shfl_xor(a, m); b2 += __shfl_xor(b2, m); }
    if (lane == 0){ Ka[o] = a + ldin<BF>(bi, o); Kb[o] = b2; }
  }
}

template<int BF>
__device__ void protonorm_body(int l, const void* Ft, const void* Pr,
                               float* invFt, float* invPr,
                               u16* FtB, u16* PrB, float* red){
  int tid = threadIdx.x;
  if (l >= Ln){
    FtB[(size_t)l*512 + tid] = 0; FtB[(size_t)l*512 + tid + 256] = 0;
    PrB[(size_t)l*512 + tid] = 0; PrB[(size_t)l*512 + tid + 256] = 0;
    return;
  }
  float a0 = ldin<BF>(Ft, l*Cn + tid), a1 = ldin<BF>(Ft, l*Cn + tid + 256);
  float p0 = ldin<BF>(Pr, l*Cn + tid), p1 = ldin<BF>(Pr, l*Cn + tid + 256);
  FtB[(size_t)l*512 + tid] = f2bf(a0); FtB[(size_t)l*512 + tid + 256] = f2bf(a1);
  PrB[(size_t)l*512 + tid] = f2bf(p0); PrB[(size_t)l*512 + tid + 256] = f2bf(p1);
  float2 r = block_red2(a0*a0 + a1*a1, p0*p0 + p1*p1, red);
  if (tid == 0){
    invFt[l] = 1.f / fmaxf(sqrtf(r.x), 1e-12f);
    invPr[l] = 1.f / fmaxf(sqrtf(r.y), 1e-12f);
  }
}

// ---- launch 1: [0,512) wconv, [512,768) kvec, [768,1792) protonorm,
//      [1792,1920) gn1 ----
__global__ __launch_bounds__(256) void k_gn1wk(const void* Fs,
    const void* W1, const void* W2, const void* W3, const void* W4,
    const void* g1, const void* g2, const void* bb1, const void* bb2,
    const void* bias1, const void* bias2,
    u16* D1, u16* D2, u16* D3, u16* D4,
    float* K1a, float* K1b, float* K2a, float* K2b,
    const void* Ft, const void* Pr, float* invFt, float* invPr, u16* FtB, u16* PrB,
    float* m1, float* rs1, u16* Fsb, float* m2s, float* m2ss){
  __shared__ float red[8];
  int bf = detect_bf(Fs);
  int blk = blockIdx.x;
  if (blk < 768){
    if (bf) wk_body<1>(blk, W1, W2, W3, W4, g1, g2, bb1, bb2, bias1, bias2,
                       D1, D2, D3, D4, K1a, K1b, K2a, K2b);
    else    wk_body<0>(blk, W1, W2, W3, W4, g1, g2, bb1, bb2, bias1, bias2,
                       D1, D2, D3, D4, K1a, K1b, K2a, K2b);
  } else if (blk < 1792){
    int l = blk - 768;
    if (bf) protonorm_body<1>(l, Ft, Pr, invFt, invPr, FtB, PrB, red);
    else    protonorm_body<0>(l, Ft, Pr, invFt, invPr, FtB, PrB, red);
  } else {
    int b = blk - 1792;
    if (bf) gn1_body<1>(b, Fs, m1, rs1, Fsb, m2s, m2ss, red);
    else    gn1_body<0>(b, Fs, m1, rs1, Fsb, m2s, m2ss, red);
  }
}

// ------- MFMA conv body, 512 threads (8 waves share one 64KB B-tile) --------
template<int C1>
__device__ void convm_body(int b, int o0,
    const u16* __restrict__ src, const u16* __restrict__ Wb,
    const float* __restrict__ Ka, const float* __restrict__ Kb,
    float mean, float rs, u16* dst, u16* Bs, float* red,
    float* m2s, float* m2ss){
  int tid = threadIdx.x;
  int lane = tid & 63, wid = tid >> 6, lq = lane & 15, g4 = lane >> 4;
  for (int idx = tid; idx < 15*64; idx += 512){
    int r = 49 + (idx >> 6), j = idx & 63;
    *(uint4*)(Bs + (r<<9) + (j<<3)) = (uint4){0,0,0,0};
  }
  #pragma unroll
  for (int is = 0; is < 7; ++is){
    int r = is*8 + wid;
    if (r < Sn){
      const u16* gsrc = src + (size_t)(b*Sn + r)*Cn + ((lane ^ (r & 7)) << 3);
      u16* ldst = Bs + (r << 9);
      __builtin_amdgcn_global_load_lds((gq_t*)gsrc, (lq_t*)ldst, 16, 0, 0);
    }
  }
  __syncthreads();
  float gs = 0.f, gss = 0.f;
  #pragma unroll
  for (int ot = 0; ot < 2; ++ot){
    int oA = o0 + wid*32 + ot*16;
    bfrag af[16];
    #pragma unroll
    for (int kb = 0; kb < 16; ++kb)
      af[kb] = *(const bfrag*)(Wb + (size_t)(oA + lq)*Cn + kb*32 + g4*8);
    ffrag acc[4];
    #pragma unroll
    for (int st = 0; st < 4; ++st) acc[st] = (ffrag){0.f,0.f,0.f,0.f};
    #pragma unroll
    for (int st = 0; st < 4; ++st){
      int srow = st*16 + lq;
      #pragma unroll
      for (int kb = 0; kb < 16; ++kb){
        bfrag bf_ = *(const bfrag*)(Bs + (srow<<9) + (((kb*4+g4) ^ (srow&7))<<3));
        acc[st] = __builtin_amdgcn_mfma_f32_16x16x32_bf16(af[kb], bf_, acc[st], 0,0,0);
      }
    }
    int ob = oA + g4*4;
    float cst[4];
    #pragma unroll
    for (int r = 0; r < 4; ++r) cst[r] = Ka[ob + r] - mean*rs*Kb[ob + r];
    #pragma unroll
    for (int st = 0; st < 4; ++st){
      int s = st*16 + lq;
      u16 pk[4];
      #pragma unroll
      for (int r = 0; r < 4; ++r){
        float val = rs*acc[st][r] + cst[r];
        if (C1){
          val = fmaxf(val, 0.f);
          if (s < Sn){ gs += val; gss += val*val; }
        }
        pk[r] = f2bf(val);
      }
      if (C1){
        if (s < Sn) *(uint2*)(dst + ((size_t)(b*Sn + s)<<9) + ob) = *(const uint2*)pk;
      } else {
        if (s >= Sn){ pk[0]=0; pk[1]=0; pk[2]=0; pk[3]=0; }
        *(uint2*)(dst + ((size_t)(b*64 + s)<<9) + ob) = *(const uint2*)pk;
      }
    }
  }
  if (C1){
    float2 r2 = block_red2_512(gs, gss, red);
    if (tid == 0){
      atomicAdd(&m2s[b], r2.x);
      atomicAdd(&m2ss[b], r2.y);
    }
  }
}

// ------------- vector MLP body, 512 threads (8 waves, 1 tile each) ----------
template<int BF, int SBF, int PH>
__device__ void vg_body(int o0, const void* src, const void* lng, const void* lnb,
    const u16* __restrict__ Wv, const void* bias, void* outp,
    u16* Bt, u16* Ach, float* mrow, float* rrow, float* Gc, float* Bc2){
  int tid = threadIdx.x, lane = tid & 63, wid = tid >> 6;
  int lq = lane & 15, g4 = lane >> 4;
  for (int c = tid; c < Cn; c += 512){ Gc[c] = ldin<BF>(lng, c); Bc2[c] = ldin<BF>(lnb, c); }
  {
    int r = tid >> 2, h = tid & 3;
    float s = 0.f, ss = 0.f;
    #pragma unroll 4
    for (int k = 0; k < 16; ++k){
      float w[8]; ld8<SBF>(src, r*Cn + h*128 + k*8, w);
      #pragma unroll
      for (int j = 0; j < 8; ++j){ s += w[j]; ss += w[j]*w[j]; }
    }
    s += __shfl_xor(s, 1); ss += __shfl_xor(ss, 1);
    s += __shfl_xor(s, 2); ss += __shfl_xor(ss, 2);
    if (h == 0){
      float m = s * (1.f/Cn);
      mrow[r] = m; rrow[r] = rsqrtf(ss * (1.f/Cn) - m*m + 1e-5f);
    }
  }
  for (int idx = tid; idx < 16*64; idx += 512){
    int row = idx >> 6, j = idx & 63;
    uint4 v = *(const uint4*)(Wv + (size_t)(o0 + row)*Cn + j*8);
    *(uint4*)(Bt + (row<<9) + ((j ^ (row&7))<<3)) = v;
  }
  __syncthreads();
  ffrag acc = (ffrag){0.f,0.f,0.f,0.f};
  for (int kc = 0; kc < 4; ++kc){
    if (kc) __syncthreads();
    for (int idx = tid; idx < 128*16; idx += 512){
      int row = idx >> 4, j = idx & 15;
      int c = kc*128 + j*8;
      float w[8]; ld8<SBF>(src, row*Cn + c, w);
      float mu = mrow[row], rsd = rrow[row];
      #pragma unroll
      for (int k2 = 0; k2 < 8; ++k2) w[k2] = (w[k2]-mu)*rsd*Gc[c+k2] + Bc2[c+k2];
      *(uint4*)(Ach + (row<<7) + ((j ^ (row&15))<<3)) = pack8(w);
    }
    __syncthreads();
    int arow = wid*16 + lq;
    #pragma unroll
    for (int kb = 0; kb < 4; ++kb){
      bfrag af = *(const bfrag*)(Ach + (arow<<7) + (((kb*4+g4) ^ (arow&15))<<3));
      bfrag bf_ = *(const bfrag*)(Bt + (lq<<9) + (((kc*16 + kb*4 + g4) ^ (lq&7))<<3));
      acc = __builtin_amdgcn_mfma_f32_16x16x32_bf16(af, bf_, acc, 0,0,0);
    }
  }
  float bval = ldin<BF>(bias, o0 + lq);
  #pragma unroll
  for (int r = 0; r < 4; ++r){
    int brow = wid*16 + g4*4 + r;
    float val = acc[r] + bval;
    if (PH == 1){
      ((u16*)outp)[brow*Cn + o0 + lq] = f2bf(fmaxf(val, 0.f));
    } else {
      ((float*)outp)[brow*Cn + o0 + lq] = val;
    }
  }
}

// LDS union: conv = 64KB Bs + 64B red; vg = 53KB carved
#define CV_SHARED __shared__ __align__(16) char smu[65600];

// ---- launch 2: vg1 (blocks 0..31) + conv1m (32..287, 2 o-slices/b) ----
__global__ __launch_bounds__(512, 2) void k_c1vg1(const void* Fs,
    const u16* Fsb, const u16* W1b, const float* Ka, const float* Kb,
    const float* m1, const float* rs1, u16* H1t, float* m2s, float* m2ss,
    const void* Fv, const void* ln1g, const void* ln1b,
    const u16* W1vb, const void* l1b, u16* Hb){
  CV_SHARED
  int blk = blockIdx.x;
  if (blk >= 32){
    u16* Bs = (u16*)smu;
    float* red = (float*)(smu + 65536);
    int cb = blk - 32;
    int b = cb >> 1, o0 = (cb & 1)*256;
    convm_body<1>(b, o0, Fsb, W1b, Ka, Kb, m1[b], rs1[b], H1t, Bs, red, m2s, m2ss);
  } else {
    u16* Bt = (u16*)smu;
    u16* Ach = (u16*)(smu + 16384);
    float* mrow = (float*)(smu + 49152);
    float* rrow = (float*)(smu + 49664);
    float* Gc = (float*)(smu + 50176);
    float* Bc2 = (float*)(smu + 52224);
    int o0 = blk*16;
    if (detect_bf(Fs)) vg_body<1,1,1>(o0, Fv, ln1g, ln1b, W1vb, l1b, Hb, Bt, Ach, mrow, rrow, Gc, Bc2);
    else               vg_body<0,0,1>(o0, Fv, ln1g, ln1b, W1vb, l1b, Hb, Bt, Ach, mrow, rrow, Gc, Bc2);
  }
}

// ---- launch 3: vg2 (blocks 0..31) + conv2m (32..287) ----
__global__ __launch_bounds__(512, 2) void k_c2vg2(const void* Fs,
    const u16* H1t, const u16* W2b, const float* Ka, const float* Kb,
    const float* m2s, const float* m2ss, u16* FspAug,
    const u16* Hb, const void* ln2g, const void* ln2b,
    const u16* W2vb, const void* l2b, float* Y2){
  CV_SHARED
  int blk = blockIdx.x;
  if (blk >= 32){
    u16* Bs = (u16*)smu;
    int cb = blk - 32;
    int b = cb >> 1, o0 = (cb & 1)*256;
    float sum = m2s[b], ssum = m2ss[b];
    float mean = sum * (1.f/(Sn*Cn));
    float var  = ssum * (1.f/(Sn*Cn)) - mean*mean;
    float rs = rsqrtf(var + 1e-5f);
    convm_body<0>(b, o0, H1t, W2b, Ka, Kb, mean, rs, FspAug, Bs,
                  (float*)nullptr, (float*)nullptr, (float*)nullptr);
  } else {
    u16* Bt = (u16*)smu;
    u16* Ach = (u16*)(smu + 16384);
    float* mrow = (float*)(smu + 49152);
    float* rrow = (float*)(smu + 49664);
    float* Gc = (float*)(smu + 50176);
    float* Bc2 = (float*)(smu + 52224);
    int o0 = blk*16;
    if (detect_bf(Fs)) vg_body<1,1,2>(o0, Hb, ln2g, ln2b, W2vb, l2b, Y2, Bt, Ach, mrow, rrow, Gc, Bc2);
    else               vg_body<0,1,2>(o0, Hb, ln2g, ln2b, W2vb, l2b, Y2, Bt, Ach, mrow, rrow, Gc, Bc2);
  }
}

// --- k_prep: Fvn = l2norm(Fvp) (fused); aug rows 56/57; G = Aug·Aug^T -------
__global__ __launch_bounds__(256) void k_prep(const float* __restrict__ Fvp,
    float* __restrict__ Fvn, u16* __restrict__ FspAug, u16* __restrict__ Gb){
  __shared__ u16 xa[64*512];
  __shared__ float red[8];
  __shared__ float fvrow[512];
  int b = blockIdx.x, tid = threadIdx.x;
  int lane = tid & 63, wid = tid >> 6, lq = lane & 15, g4 = lane >> 4;
  float x0 = Fvp[b*Cn + tid], x1 = Fvp[b*Cn + tid + 256];
  float2 rr = block_red2(x0*x0 + x1*x1, 0.f, red);
  float inv = 1.f / fmaxf(sqrtf(rr.x), 1e-12f);
  fvrow[tid] = x0*inv; fvrow[tid + 256] = x1*inv;
  Fvn[b*Cn + tid] = x0*inv; Fvn[b*Cn + tid + 256] = x1*inv;
  __syncthreads();
  for (int idx = tid; idx < 64*64; idx += 256){
    int s = idx >> 6, j = idx & 63;
    uint4 v;
    if (s == 56 || s == 57){
      float w[8];
      if (s == 56){
        const float* src = Fvp + b*Cn + j*8;
        #pragma unroll
        for (int k = 0; k < 8; ++k) w[k] = src[k];
      } else {
        #pragma unroll
        for (int k = 0; k < 8; ++k) w[k] = fvrow[j*8 + k];
      }
      v = pack8(w);
      *(uint4*)(FspAug + ((size_t)(b*64 + s))*512 + j*8) = v;
    } else {
      v = *(const uint4*)(FspAug + ((size_t)(b*64 + s))*512 + j*8);
    }
    *(uint4*)(xa + s*512 + ((j ^ (s&7)) << 3)) = v;
  }
  __syncthreads();
  int mt = wid;
  for (int nt = 0; nt < 4; ++nt){
    ffrag acc = {0.f, 0.f, 0.f, 0.f};
    #pragma unroll
    for (int kb = 0; kb < 16; ++kb){
      int j = kb*4 + g4;
      int rowa = mt*16 + lq, rowb = nt*16 + lq;
      bfrag af  = *(const bfrag*)(xa + rowa*512 + ((j ^ (rowa&7)) << 3));
      bfrag bf_ = *(const bfrag*)(xa + rowb*512 + ((j ^ (rowb&7)) << 3));
      acc = __builtin_amdgcn_mfma_f32_16x16x32_bf16(af, bf_, acc, 0, 0, 0);
    }
    #pragma unroll
    for (int r = 0; r < 4; ++r)
      Gb[(size_t)b*4096 + (mt*16 + g4*4 + r)*64 + nt*16 + lq] = f2bf(acc[r]);
  }
}

// ------- K1: scores GEMM -> f16; async staging; grid (Bn, 8) ---------------
__global__ __launch_bounds__(256, 3) void k_scores(const u16* __restrict__ LB,
    const u16* __restrict__ FspAug, u16* __restrict__ Sc){
  __shared__ u16 At[64*256];   // 32768 B
  int b = blockIdx.x, lg = blockIdx.y;
  int tid = threadIdx.x, lane = tid & 63, wid = tid >> 6;
  int lq = lane & 15, g4 = lane >> 4;
  int l32 = lane & 31, rh = lane >> 5;
  bfrag breg[16];
  {
    const u16* fa = FspAug + ((size_t)(b*64 + wid*16 + lq))*512 + g4*8;
    #pragma unroll
    for (int kb = 0; kb < 16; ++kb) breg[kb] = *(const bfrag*)(fa + kb*32);
  }
  for (int chunk = 0; chunk < 4; ++chunk){
    int qi = lg*4 + chunk;
    ffrag acc[4];
    #pragma unroll
    for (int lt = 0; lt < 4; ++lt) acc[lt] = (ffrag){0.f,0.f,0.f,0.f};
    for (int kc = 0; kc < 2; ++kc){
      __syncthreads();   // guard At rewrite
      #pragma unroll
      for (int is = 0; is < 8; ++is){
        int r = (is*4 + wid)*2 + rh;
        const u16* gsrc = LB + (size_t)(qi*64 + r)*512 + kc*256 + ((l32 ^ (r & 7)) << 3);
        u16* ldst = At + ((is*4 + wid) << 9);
        __builtin_amdgcn_global_load_lds((gq_t*)gsrc, (lq_t*)ldst, 16, 0, 0);
      }
      __syncthreads();
      #pragma unroll
      for (int kb = 0; kb < 8; ++kb){
        #pragma unroll
        for (int lt = 0; lt < 4; ++lt){
          int row = lt*16 + lq;
          bfrag af = *(const bfrag*)(At + (row<<8) + (((kb*4+g4) ^ (row&7))<<3));
          acc[lt] = __builtin_amdgcn_mfma_f32_16x16x32_bf16(af, breg[kc*8+kb], acc[lt], 0,0,0);
        }
      }
    }
    #pragma unroll
    for (int lt = 0; lt < 4; ++lt){
      #pragma unroll
      for (int r = 0; r < 4; ++r){
        size_t row = (size_t)b*VQ + qi*64 + lt*16 + g4*4 + r;
        Sc[row*64 + wid*16 + lq] = f2h(acc[lt][r]);
      }
    }
  }
}

// -- K2: row-per-lane softmax + gram epilogue; blocks >= 4096 do proto update
__global__ __launch_bounds__(64) void k_attn4(const void* Fs,
    const u16* __restrict__ Sc, const u16* __restrict__ Gb,
    const float* __restrict__ invFt, const float* __restrict__ invPr,
    const void* gp_, const void* gn_,
    const int* __restrict__ label, const float* __restrict__ Fvn,
    const void* Pr, float* __restrict__ out){
  __shared__ u16 a1t[64*72];
  __shared__ float agab[64], wvb[64];
  __shared__ int lab[128];
  int bid = blockIdx.x;
  int bf = detect_bf(Fs);
  int lane = threadIdx.x;
  if (bid >= 4096){
    int l = bid - 4096;
    lab[lane] = label[lane]; lab[lane + 64] = label[lane + 64];
    __syncthreads();
    float sum[8] = {0.f,0.f,0.f,0.f,0.f,0.f,0.f,0.f};
    int cnt = 0;
    for (int i = 0; i < Bn; ++i){
      if (lab[i] == l){
        cnt++;
        const float4* v = (const float4*)(Fvn + i*Cn + lane*8);
        float4 a = v[0], c = v[1];
        sum[0]+=a.x; sum[1]+=a.y; sum[2]+=a.z; sum[3]+=a.w;
        sum[4]+=c.x; sum[5]+=c.y; sum[6]+=c.z; sum[7]+=c.w;
      }
    }
    int base = l*Cn + lane*8;
    float* dst = out + 3*BL + base;
    if (cnt > 0){
      float sc = 0.01f / fmaxf((float)cnt, 1e-8f);
      #pragma unroll
      for (int j = 0; j < 8; ++j)
        dst[j] = 0.99f*(bf ? ldin<1>(Pr, base+j) : ldin<0>(Pr, base+j)) + sum[j]*sc;
    } else {
      #pragma unroll
      for (int j = 0; j < 8; ++j)
        dst[j] = bf ? ldin<1>(Pr, base+j) : ldin<0>(Pr, base+j);
    }
    return;
  }
  int qi = bid & 31, b = bid >> 5;
  int lq = lane & 15, g4 = lane >> 4;

  u32 w32[32];
  {
    const uint4* rp = (const uint4*)(Sc + ((size_t)b*VQ + qi*64 + lane)*64);
    #pragma unroll
    for (int i = 0; i < 8; ++i){
      uint4 v = rp[i];
      w32[i*4+0] = v.x; w32[i*4+1] = v.y; w32[i*4+2] = v.z; w32[i*4+3] = v.w;
    }
  }
  #define XS(s) h2f((u16)(((s)&1) ? (w32[(s)>>1] >> 16) : (w32[(s)>>1] & 0xffffu)))
  float mx = -1e30f;
  #pragma unroll
  for (int s = 0; s < Sn; ++s) mx = fmaxf(mx, XS(s));
  float raw56 = XS(56), raw57 = XS(57);
  float sm = 0.f, dx = 0.f;
  #pragma unroll
  for (int u = 0; u < 7; ++u){
    u32 pw[4];
    #pragma unroll
    for (int i = 0; i < 4; ++i){
      u32 w2 = 0;
      #pragma unroll
      for (int h = 0; h < 2; ++h){
        int s = u*8 + i*2 + h;
        float x = XS(s);
        float e = (s < Sn) ? __expf(x - mx) : 0.f;
        sm += e; dx += e * x;
        w2 |= ((u32)f2bf(e)) << (16*h);
      }
      pw[i] = w2;
    }
    *(uint4*)(a1t + lane*72 + u*8) = make_uint4(pw[0], pw[1], pw[2], pw[3]);
  }
  #undef XS

  const u16* gbase = Gb + (size_t)b*4096;
  #pragma unroll
  for (int qt = 0; qt < 4; ++qt){
    float pr[4] = {0.f, 0.f, 0.f, 0.f};
    float wvl[4] = {0.f, 0.f, 0.f, 0.f};
    #pragma unroll
    for (int nt = 0; nt < 4; ++nt){
      ffrag acc = {0.f, 0.f, 0.f, 0.f};
      #pragma unroll
      for (int kb2 = 0; kb2 < 2; ++kb2){
        bfrag af;
        if (kb2 == 1 && g4 == 3) af = (bfrag){0,0,0,0,0,0,0,0};
        else af = *(const bfrag*)(a1t + (qt*16 + lq)*72 + (g4 + 4*kb2)*8);
        bfrag bg = *(const bfrag*)(gbase + (nt*16 + lq)*64 + kb2*32 + g4*8);
        acc = __builtin_amdgcn_mfma_f32_16x16x32_bf16(af, bg, acc, 0, 0, 0);
      }
      int sp = nt*16 + lq;
      #pragma unroll
      for (int r = 0; r < 4; ++r){
        int q = qt*16 + g4*4 + r;
        float av = (sp < 56) ? bf2f(a1t[q*72 + sp]) : 0.f;
        pr[r] += av * acc[r];
        if (nt == 3 && lq == 8) wvl[r] = acc[r];
      }
    }
    #pragma unroll
    for (int m = 1; m <= 8; m <<= 1){
      #pragma unroll
      for (int r = 0; r < 4; ++r) pr[r] += __shfl_xor(pr[r], m);
    }
    if (lq == 0){
      #pragma unroll
      for (int r = 0; r < 4; ++r) agab[qt*16 + g4*4 + r] = pr[r];
    }
    if (lq == 8){
      #pragma unroll
      for (int r = 0; r < 4; ++r) wvb[qt*16 + g4*4 + r] = wvl[r];
    }
  }

  int vq = qi*64 + lane;
  int path = vq >> 10, l = vq & 1023;
  if (l < Ln){
    float gp = ld_gamma(gp_, bf), gn = ld_gamma(gn_, bf);
    float fvpSq = bf2f(gbase[56*64 + 56]);
    float inv_sm = 1.f / sm;
    float aGa = agab[lane] * inv_sm * inv_sm;
    float wv  = wvb[lane] * inv_sm;
    float gam = path ? gn : gp;
    float ns  = gam*gam*aGa + 2.f*gam*wv + fvpSq;
    float dt  = gam*(dx*inv_sm) + raw56;
    float invx = (path ? invPr : invFt)[l];
    float lg2 = dt * invx / fmaxf(sqrtf(ns), 1e-12f);
    if (path == 0){
      out[(size_t)b*Ln + l]              = raw57 * invx;
      out[(size_t)BL + (size_t)b*Ln + l] = lg2;
    } else {
      out[(size_t)2*BL + (size_t)b*Ln + l] = lg2;
    }
  }
}

// ---------------------------------------------------------------------------
extern "C" void kernel_launch(void* const* d_in, const int* in_sizes, int n_in,
                              void* d_out, int out_size, void* d_ws, size_t ws_size,
                              hipStream_t stream){
  (void)in_sizes; (void)n_in; (void)out_size; (void)ws_size;
  const void* Fs    = d_in[0];
  const void* Ft    = d_in[1];
  const void* Fv    = d_in[2];
  const int*  label = (const int*)d_in[3];
  const void* gn1g  = d_in[4];
  const void* gn1b  = d_in[5];
  const void* c1w   = d_in[6];
  const void* c1b   = d_in[7];
  const void* gn2g  = d_in[8];
  const void* gn2b  = d_in[9];
  const void* c2w   = d_in[10];
  const void* c2b   = d_in[11];
  const void* ln1g  = d_in[12];
  const void* ln1b  = d_in[13];
  const void* l1w   = d_in[14];
  const void* l1b   = d_in[15];
  const void* ln2g  = d_in[16];
  const void* ln2b  = d_in[17];
  const void* l2w   = d_in[18];
  const void* l2b   = d_in[19];
  const void* gp    = d_in[20];
  const void* gnm   = d_in[21];
  const void* proto = d_in[22];
  float* out = (float*)d_out;
  float* ws  = (float*)d_ws;

  float* m1    = ws + 0;
  float* rs1   = ws + 128;
  float* m2s   = ws + 256;
  float* m2ss  = ws + 384;
  float* invFt = ws + 512;
  float* invPr = ws + 1536;
  u16*   H1t   = (u16*)(ws + 4096);                 // B*49*512 bf16
  float* Fvp   = ws + 4096 + (size_t)Bn*Sn*Cn/2;    // B*C f32
  float* Fvn   = Fvp + Bn*Cn;
  u16*   FspAug= (u16*)(Fvn + Bn*Cn);               // B*64*512 bf16
  u16*   FtB   = FspAug + (size_t)Bn*64*512;        // 1024*512 bf16 (PrB follows)
  u16*   PrB   = FtB + (size_t)1024*512;
  u16*   Gb    = PrB + (size_t)1024*512;            // B*64*64 bf16
  u16*   W1b   = Gb + (size_t)Bn*4096;              // 512*512 bf16 x4
  u16*   W2b   = W1b + (size_t)512*512;
  u16*   W1vb  = W2b + (size_t)512*512;
  u16*   W2vb  = W1vb + (size_t)512*512;
  u16*   Hb    = W2vb + (size_t)512*512;            // 128*512 bf16
  u16*   Fsb   = Hb + (size_t)Bn*Cn;                // B*49*512 bf16
  float* Kv1a  = (float*)(Fsb + (size_t)Bn*Sn*Cn);  // 4 x 512 f32
  float* Kv1b  = Kv1a + 512;
  float* Kv2a  = Kv1b + 512;
  float* Kv2b  = Kv2a + 512;
  u16*   Sc    = (u16*)(Kv2b + 512);                // B*2048*64 f16 (33.5MB)

  k_gn1wk<<<1920, 256, 0, stream>>>(Fs, c1w, c2w, l1w, l2w, gn1g, gn2g,
                                    gn1b, gn2b, c1b, c2b,
                                    W1b, W2b, W1vb, W2vb, Kv1a, Kv1b, Kv2a, Kv2b,
                                    Ft, proto, invFt, invPr, FtB, PrB,
                                    m1, rs1, Fsb, m2s, m2ss);
  k_c1vg1<<<288, 512, 0, stream>>>(Fs, Fsb, W1b, Kv1a, Kv1b, m1, rs1, H1t, m2s, m2ss,
                                   Fv, ln1g, ln1b, W1vb, l1b, Hb);
  k_c2vg2<<<288, 512, 0, stream>>>(Fs, H1t, W2b, Kv2a, Kv2b, m2s, m2ss, FspAug,
                                   Hb, ln2g, ln2b, W2vb, l2b, Fvp);
  k_prep<<<Bn, 256, 0, stream>>>(Fvp, Fvn, FspAug, Gb);
  k_scores<<<dim3(Bn, 8), 256, 0, stream>>>(FtB, FspAug, Sc);
  k_attn4<<<4096 + Ln, 64, 0, stream>>>(Fs, Sc, Gb, invFt, invPr, gp, gnm,
                                        label, Fvn, proto, out);
}

// Round 23
// 136.423 us; speedup vs baseline: 1.2123x; 1.0014x over previous
//
#include <hip/hip_runtime.h>

// ---------------------------------------------------------------------------
// DPM_Block — Round 22: R21 base (141.5us) + 512-thread conv/vg with the
// CORRECTED bound (512,2): 2 blocks/CU x 8 waves = 16 waves/CU, VGPR cap 128
// (R19's (512,4) meant 4 blocks/CU -> cap 64 -> spill cliff).
// ---------------------------------------------------------------------------

#define Bn 128
#define Sn 49
#define Cn 512
#define Ln 1000
#define BL (Bn*Ln)
#define VQ 2048

typedef unsigned short u16;
typedef unsigned int u32;

using bfrag = __attribute__((ext_vector_type(8))) short;   // 8 bf16 (4 VGPR)
using ffrag = __attribute__((ext_vector_type(4))) float;   // 4 f32 acc

typedef const __attribute__((address_space(1))) u32 gq_t;
typedef __attribute__((address_space(3))) u32 lq_t;

__device__ __forceinline__ float bf2f(u16 u){ return __uint_as_float(((u32)u) << 16); }
__device__ __forceinline__ float bflo(u32 u){ return __uint_as_float(u << 16); }
__device__ __forceinline__ float bfhi(u32 u){ return __uint_as_float(u & 0xffff0000u); }
__device__ __forceinline__ u16 f2bf(float f){
  u32 x = __float_as_uint(f);
  u32 r = x + 0x7fffu + ((x >> 16) & 1u);   // RNE
  return (u16)(r >> 16);
}
__device__ __forceinline__ u16 f2h(float f){
  _Float16 h = (_Float16)f; return *(u16*)&h;
}
__device__ __forceinline__ float h2f(u16 u){
  _Float16 h = *(_Float16*)&u; return (float)h;
}

template<int BF>
__device__ __forceinline__ float ldin(const void* p, int i){
  if (BF) return bf2f(((const u16*)p)[i]);
  return ((const float*)p)[i];
}

template<int BF>
__device__ __forceinline__ void ld8(const void* p, int base, float* w){
  if (BF){
    uint4 u = *(const uint4*)((const u16*)p + base);
    w[0]=bflo(u.x); w[1]=bfhi(u.x); w[2]=bflo(u.y); w[3]=bfhi(u.y);
    w[4]=bflo(u.z); w[5]=bfhi(u.z); w[6]=bflo(u.w); w[7]=bfhi(u.w);
  } else {
    float4 a = *(const float4*)((const float*)p + base);
    float4 b = *(const float4*)((const float*)p + base + 4);
    w[0]=a.x; w[1]=a.y; w[2]=a.z; w[3]=a.w;
    w[4]=b.x; w[5]=b.y; w[6]=b.z; w[7]=b.w;
  }
}

__device__ __forceinline__ uint4 pack8(const float* w){
  uint4 v;
  v.x = (u32)f2bf(w[0]) | ((u32)f2bf(w[1])<<16);
  v.y = (u32)f2bf(w[2]) | ((u32)f2bf(w[3])<<16);
  v.z = (u32)f2bf(w[4]) | ((u32)f2bf(w[5])<<16);
  v.w = (u32)f2bf(w[6]) | ((u32)f2bf(w[7])<<16);
  return v;
}

__device__ __forceinline__ float ld_gamma(const void* p, int BF){
  float fb = bf2f(((const u16*)p)[0]);
  float ff = ((const float*)p)[0];
  bool pb = (fb > 0.05f && fb < 1.5f);
  bool pf = (ff > 0.05f && ff < 1.5f);
  if (pb && !pf) return fb;
  if (pf && !pb) return ff;
  return BF ? fb : ff;
}

// ---- inline dtype detector ----
__device__ __forceinline__ int detect_bf(const void* Fs){
  int lane = threadIdx.x & 63;
  uint4 v = ((const uint4*)Fs)[lane];
  u32 w[4] = {v.x, v.y, v.z, v.w};
  int c = 0;
  #pragma unroll
  for (int j = 0; j < 4; ++j){
    int e = (w[j] >> 7) & 0xff;
    c += (e >= 0x70 && e <= 0x8f);
  }
  #pragma unroll
  for (int m = 32; m; m >>= 1) c += __shfl_xor(c, m);
  return c >= 200;
}

// 256-thread block reduction
__device__ __forceinline__ float2 block_red2(float a, float b, float* scratch){
  __syncthreads();
  #pragma unroll
  for (int off = 32; off; off >>= 1){ a += __shfl_xor(a, off); b += __shfl_xor(b, off); }
  int lane = threadIdx.x & 63, wid = threadIdx.x >> 6;
  if (lane == 0){ scratch[wid] = a; scratch[wid + 4] = b; }
  __syncthreads();
  return make_float2(scratch[0] + scratch[1] + scratch[2] + scratch[3],
                     scratch[4] + scratch[5] + scratch[6] + scratch[7]);
}

// 512-thread block reduction (scratch 16 floats)
__device__ __forceinline__ float2 block_red2_512(float a, float b, float* scratch){
  __syncthreads();
  #pragma unroll
  for (int off = 32; off; off >>= 1){ a += __shfl_xor(a, off); b += __shfl_xor(b, off); }
  int lane = threadIdx.x & 63, wid = threadIdx.x >> 6;
  if (lane == 0){ scratch[wid] = a; scratch[wid + 8] = b; }
  __syncthreads();
  float ra = 0.f, rb = 0.f;
  #pragma unroll
  for (int i = 0; i < 8; ++i){ ra += scratch[i]; rb += scratch[i + 8]; }
  return make_float2(ra, rb);
}

// -------------------- bodies --------------------
template<int BF>
__device__ void gn1_body(int b, const void* Fs, float* m1, float* rs1, u16* Fsb,
                         float* m2s, float* m2ss, float* red){
  int tid = threadIdx.x;
  if (tid == 0){ m2s[b] = 0.f; m2ss[b] = 0.f; }
  float s = 0.f, ss = 0.f;
  for (int i = tid; i < Sn*Cn/8; i += 256){
    float w[8]; ld8<BF>(Fs, b*Sn*Cn + i*8, w);
    #pragma unroll
    for (int j = 0; j < 8; ++j){ s += w[j]; ss += w[j]*w[j]; }
    *(uint4*)(Fsb + (size_t)b*Sn*Cn + i*8) = pack8(w);
  }
  float2 r = block_red2(s, ss, red);
  if (tid == 0){
    float m = r.x * (1.f/(Sn*Cn));
    float v = r.y * (1.f/(Sn*Cn)) - m*m;
    m1[b] = m; rs1[b] = rsqrtf(v + 1e-5f);
  }
}

template<int BF>
__device__ void wk_body(int blk, const void* W1, const void* W2, const void* W3,
    const void* W4, const void* g1, const void* g2, const void* bb1, const void* bb2,
    const void* bias1, const void* bias2,
    u16* D1, u16* D2, u16* D3, u16* D4,
    float* K1a, float* K1b, float* K2a, float* K2b){
  if (blk < 512){
    int i = blk*256 + threadIdx.x;
    int sel = i >> 15;
    const void* src = (sel==0) ? W1 : (sel==1) ? W2 : (sel==2) ? W3 : W4;
    u16* dst = (sel==0) ? D1 : (sel==1) ? D2 : (sel==2) ? D3 : D4;
    int off = (i & 32767)*8;
    float w[8]; ld8<BF>(src, off, w);
    if (sel <= 1){
      const void* g = sel ? g2 : g1;
      int c0 = off & 511;
      #pragma unroll
      for (int j = 0; j < 8; ++j) w[j] *= ldin<BF>(g, c0 + j);
    }
    *(uint4*)(dst + off) = pack8(w);
  } else {
    int idx = (blk - 512)*4 + (threadIdx.x >> 6);
    int lane = threadIdx.x & 63;
    int o = idx & 511, sel = idx >> 9;
    const void* W  = sel ? W2 : W1;
    const void* g  = sel ? g2 : g1;
    const void* bb = sel ? bb2 : bb1;
    const void* bi = sel ? bias2 : bias1;
    float* Ka = sel ? K2a : K1a;
    float* Kb = sel ? K2b : K1b;
    float w[8], gv[8], bv[8];
    ld8<BF>(W, o*Cn + lane*8, w);
    ld8<BF>(g, lane*8, gv);
    ld8<BF>(bb, lane*8, bv);
    float a = 0.f, b2 = 0.f;
    #pragma unroll
    for (int j = 0; j < 8; ++j){ a += w[j]*bv[j]; b2 += w[j]*gv[j]; }
    #pragma unroll
    for (int m = 32; m; m >>= 1){ a += __shfl_xor(a, m); b2 += __shfl_xor(b2, m); }
    if (lane == 0){ Ka[o] = a + ldin<BF>(bi, o); Kb[o] = b2; }
  }
}

template<int BF>
__device__ void protonorm_body(int l, const void* Ft, const void* Pr,
                               float* invFt, float* invPr,
                               u16* FtB, u16* PrB, float* red){
  int tid = threadIdx.x;
  if (l >= Ln){
    FtB[(size_t)l*512 + tid] = 0; FtB[(size_t)l*512 + tid + 256] = 0;
    PrB[(size_t)l*512 + tid] = 0; PrB[(size_t)l*512 + tid + 256] = 0;
    return;
  }
  float a0 = ldin<BF>(Ft, l*Cn + tid), a1 = ldin<BF>(Ft, l*Cn + tid + 256);
  float p0 = ldin<BF>(Pr, l*Cn + tid), p1 = ldin<BF>(Pr, l*Cn + tid + 256);
  FtB[(size_t)l*512 + tid] = f2bf(a0); FtB[(size_t)l*512 + tid + 256] = f2bf(a1);
  PrB[(size_t)l*512 + tid] = f2bf(p0); PrB[(size_t)l*512 + tid + 256] = f2bf(p1);
  float2 r = block_red2(a0*a0 + a1*a1, p0*p0 + p1*p1, red);
  if (tid == 0){
    invFt[l] = 1.f / fmaxf(sqrtf(r.x), 1e-12f);
    invPr[l] = 1.f / fmaxf(sqrtf(r.y), 1e-12f);
  }
}

// ---- launch 1: [0,512) wconv, [512,768) kvec, [768,1792) protonorm,
//      [1792,1920) gn1 ----
__global__ __launch_bounds__(256) void k_gn1wk(const void* Fs,
    const void* W1, const void* W2, const void* W3, const void* W4,
    const void* g1, const void* g2, const void* bb1, const void* bb2,
    const void* bias1, const void* bias2,
    u16* D1, u16* D2, u16* D3, u16* D4,
    float* K1a, float* K1b, float* K2a, float* K2b,
    const void* Ft, const void* Pr, float* invFt, float* invPr, u16* FtB, u16* PrB,
    float* m1, float* rs1, u16* Fsb, float* m2s, float* m2ss){
  __shared__ float red[8];
  int bf = detect_bf(Fs);
  int blk = blockIdx.x;
  if (blk < 768){
    if (bf) wk_body<1>(blk, W1, W2, W3, W4, g1, g2, bb1, bb2, bias1, bias2,
                       D1, D2, D3, D4, K1a, K1b, K2a, K2b);
    else    wk_body<0>(blk, W1, W2, W3, W4, g1, g2, bb1, bb2, bias1, bias2,
                       D1, D2, D3, D4, K1a, K1b, K2a, K2b);
  } else if (blk < 1792){
    int l = blk - 768;
    if (bf) protonorm_body<1>(l, Ft, Pr, invFt, invPr, FtB, PrB, red);
    else    protonorm_body<0>(l, Ft, Pr, invFt, invPr, FtB, PrB, red);
  } else {
    int b = blk - 1792;
    if (bf) gn1_body<1>(b, Fs, m1, rs1, Fsb, m2s, m2ss, red);
    else    gn1_body<0>(b, Fs, m1, rs1, Fsb, m2s, m2ss, red);
  }
}

// ------- MFMA conv body, 512 threads (8 waves share one 64KB B-tile) --------
template<int C1>
__device__ void convm_body(int b, int o0,
    const u16* __restrict__ src, const u16* __restrict__ Wb,
    const float* __restrict__ Ka, const float* __restrict__ Kb,
    float mean, float rs, u16* dst, u16* Bs, float* red,
    float* m2s, float* m2ss){
  int tid = threadIdx.x;
  int lane = tid & 63, wid = tid >> 6, lq = lane & 15, g4 = lane >> 4;
  for (int idx = tid; idx < 15*64; idx += 512){
    int r = 49 + (idx >> 6), j = idx & 63;
    *(uint4*)(Bs + (r<<9) + (j<<3)) = (uint4){0,0,0,0};
  }
  #pragma unroll
  for (int is = 0; is < 7; ++is){
    int r = is*8 + wid;
    if (r < Sn){
      const u16* gsrc = src + (size_t)(b*Sn + r)*Cn + ((lane ^ (r & 7)) << 3);
      u16* ldst = Bs + (r << 9);
      __builtin_amdgcn_global_load_lds((gq_t*)gsrc, (lq_t*)ldst, 16, 0, 0);
    }
  }
  __syncthreads();
  float gs = 0.f, gss = 0.f;
  #pragma unroll
  for (int ot = 0; ot < 2; ++ot){
    int oA = o0 + wid*32 + ot*16;
    bfrag af[16];
    #pragma unroll
    for (int kb = 0; kb < 16; ++kb)
      af[kb] = *(const bfrag*)(Wb + (size_t)(oA + lq)*Cn + kb*32 + g4*8);
    ffrag acc[4];
    #pragma unroll
    for (int st = 0; st < 4; ++st) acc[st] = (ffrag){0.f,0.f,0.f,0.f};
    #pragma unroll
    for (int st = 0; st < 4; ++st){
      int srow = st*16 + lq;
      #pragma unroll
      for (int kb = 0; kb < 16; ++kb){
        bfrag bf_ = *(const bfrag*)(Bs + (srow<<9) + (((kb*4+g4) ^ (srow&7))<<3));
        acc[st] = __builtin_amdgcn_mfma_f32_16x16x32_bf16(af[kb], bf_, acc[st], 0,0,0);
      }
    }
    int ob = oA + g4*4;
    float cst[4];
    #pragma unroll
    for (int r = 0; r < 4; ++r) cst[r] = Ka[ob + r] - mean*rs*Kb[ob + r];
    #pragma unroll
    for (int st = 0; st < 4; ++st){
      int s = st*16 + lq;
      u16 pk[4];
      #pragma unroll
      for (int r = 0; r < 4; ++r){
        float val = rs*acc[st][r] + cst[r];
        if (C1){
          val = fmaxf(val, 0.f);
          if (s < Sn){ gs += val; gss += val*val; }
        }
        pk[r] = f2bf(val);
      }
      if (C1){
        if (s < Sn) *(uint2*)(dst + ((size_t)(b*Sn + s)<<9) + ob) = *(const uint2*)pk;
      } else {
        if (s >= Sn){ pk[0]=0; pk[1]=0; pk[2]=0; pk[3]=0; }
        *(uint2*)(dst + ((size_t)(b*64 + s)<<9) + ob) = *(const uint2*)pk;
      }
    }
  }
  if (C1){
    float2 r2 = block_red2_512(gs, gss, red);
    if (tid == 0){
      atomicAdd(&m2s[b], r2.x);
      atomicAdd(&m2ss[b], r2.y);
    }
  }
}

// ------------- vector MLP body, 512 threads (8 waves, 1 tile each) ----------
template<int BF, int SBF, int PH>
__device__ void vg_body(int o0, const void* src, const void* lng, const void* lnb,
    const u16* __restrict__ Wv, const void* bias, void* outp,
    u16* Bt, u16* Ach, float* mrow, float* rrow, float* Gc, float* Bc2){
  int tid = threadIdx.x, lane = tid & 63, wid = tid >> 6;
  int lq = lane & 15, g4 = lane >> 4;
  for (int c = tid; c < Cn; c += 512){ Gc[c] = ldin<BF>(lng, c); Bc2[c] = ldin<BF>(lnb, c); }
  {
    int r = tid >> 2, h = tid & 3;
    float s = 0.f, ss = 0.f;
    #pragma unroll 4
    for (int k = 0; k < 16; ++k){
      float w[8]; ld8<SBF>(src, r*Cn + h*128 + k*8, w);
      #pragma unroll
      for (int j = 0; j < 8; ++j){ s += w[j]; ss += w[j]*w[j]; }
    }
    s += __shfl_xor(s, 1); ss += __shfl_xor(ss, 1);
    s += __shfl_xor(s, 2); ss += __shfl_xor(ss, 2);
    if (h == 0){
      float m = s * (1.f/Cn);
      mrow[r] = m; rrow[r] = rsqrtf(ss * (1.f/Cn) - m*m + 1e-5f);
    }
  }
  for (int idx = tid; idx < 16*64; idx += 512){
    int row = idx >> 6, j = idx & 63;
    uint4 v = *(const uint4*)(Wv + (size_t)(o0 + row)*Cn + j*8);
    *(uint4*)(Bt + (row<<9) + ((j ^ (row&7))<<3)) = v;
  }
  __syncthreads();
  ffrag acc = (ffrag){0.f,0.f,0.f,0.f};
  for (int kc = 0; kc < 4; ++kc){
    if (kc) __syncthreads();
    for (int idx = tid; idx < 128*16; idx += 512){
      int row = idx >> 4, j = idx & 15;
      int c = kc*128 + j*8;
      float w[8]; ld8<SBF>(src, row*Cn + c, w);
      float mu = mrow[row], rsd = rrow[row];
      #pragma unroll
      for (int k2 = 0; k2 < 8; ++k2) w[k2] = (w[k2]-mu)*rsd*Gc[c+k2] + Bc2[c+k2];
      *(uint4*)(Ach + (row<<7) + ((j ^ (row&15))<<3)) = pack8(w);
    }
    __syncthreads();
    int arow = wid*16 + lq;
    #pragma unroll
    for (int kb = 0; kb < 4; ++kb){
      bfrag af = *(const bfrag*)(Ach + (arow<<7) + (((kb*4+g4) ^ (arow&15))<<3));
      bfrag bf_ = *(const bfrag*)(Bt + (lq<<9) + (((kc*16 + kb*4 + g4) ^ (lq&7))<<3));
      acc = __builtin_amdgcn_mfma_f32_16x16x32_bf16(af, bf_, acc, 0,0,0);
    }
  }
  float bval = ldin<BF>(bias, o0 + lq);
  #pragma unroll
  for (int r = 0; r < 4; ++r){
    int brow = wid*16 + g4*4 + r;
    float val = acc[r] + bval;
    if (PH == 1){
      ((u16*)outp)[brow*Cn + o0 + lq] = f2bf(fmaxf(val, 0.f));
    } else {
      ((float*)outp)[brow*Cn + o0 + lq] = val;
    }
  }
}

// LDS union: conv = 64KB Bs + 64B red; vg = 53KB carved
#define CV_SHARED __shared__ __align__(16) char smu[65600];

// ---- launch 2: vg1 (blocks 0..31) + conv1m (32..287, 2 o-slices/b) ----
__global__ __launch_bounds__(512, 2) void k_c1vg1(const void* Fs,
    const u16* Fsb, const u16* W1b, const float* Ka, const float* Kb,
    const float* m1, const float* rs1, u16* H1t, float* m2s, float* m2ss,
    const void* Fv, const void* ln1g, const void* ln1b,
    const u16* W1vb, const void* l1b, u16* Hb){
  CV_SHARED
  int blk = blockIdx.x;
  if (blk >= 32){
    u16* Bs = (u16*)smu;
    float* red = (float*)(smu + 65536);
    int cb = blk - 32;
    int b = cb >> 1, o0 = (cb & 1)*256;
    convm_body<1>(b, o0, Fsb, W1b, Ka, Kb, m1[b], rs1[b], H1t, Bs, red, m2s, m2ss);
  } else {
    u16* Bt = (u16*)smu;
    u16* Ach = (u16*)(smu + 16384);
    float* mrow = (float*)(smu + 49152);
    float* rrow = (float*)(smu + 49664);
    float* Gc = (float*)(smu + 50176);
    float* Bc2 = (float*)(smu + 52224);
    int o0 = blk*16;
    if (detect_bf(Fs)) vg_body<1,1,1>(o0, Fv, ln1g, ln1b, W1vb, l1b, Hb, Bt, Ach, mrow, rrow, Gc, Bc2);
    else               vg_body<0,0,1>(o0, Fv, ln1g, ln1b, W1vb, l1b, Hb, Bt, Ach, mrow, rrow, Gc, Bc2);
  }
}

// ---- launch 3: vg2 (blocks 0..31) + conv2m (32..287) ----
__global__ __launch_bounds__(512, 2) void k_c2vg2(const void* Fs,
    const u16* H1t, const u16* W2b, const float* Ka, const float* Kb,
    const float* m2s, const float* m2ss, u16* FspAug,
    const u16* Hb, const void* ln2g, const void* ln2b,
    const u16* W2vb, const void* l2b, float* Y2){
  CV_SHARED
  int blk = blockIdx.x;
  if (blk >= 32){
    u16* Bs = (u16*)smu;
    int cb = blk - 32;
    int b = cb >> 1, o0 = (cb & 1)*256;
    float sum = m2s[b], ssum = m2ss[b];
    float mean = sum * (1.f/(Sn*Cn));
    float var  = ssum * (1.f/(Sn*Cn)) - mean*mean;
    float rs = rsqrtf(var + 1e-5f);
    convm_body<0>(b, o0, H1t, W2b, Ka, Kb, mean, rs, FspAug, Bs,
                  (float*)nullptr, (float*)nullptr, (float*)nullptr);
  } else {
    u16* Bt = (u16*)smu;
    u16* Ach = (u16*)(smu + 16384);
    float* mrow = (float*)(smu + 49152);
    float* rrow = (float*)(smu + 49664);
    float* Gc = (float*)(smu + 50176);
    float* Bc2 = (float*)(smu + 52224);
    int o0 = blk*16;
    if (detect_bf(Fs)) vg_body<1,1,2>(o0, Hb, ln2g, ln2b, W2vb, l2b, Y2, Bt, Ach, mrow, rrow, Gc, Bc2);
    else               vg_body<0,1,2>(o0, Hb, ln2g, ln2b, W2vb, l2b, Y2, Bt, Ach, mrow, rrow, Gc, Bc2);
  }
}

// --- k_prep: Fvn = l2norm(Fvp) (fused); aug rows 56/57; G = Aug·Aug^T -------
__global__ __launch_bounds__(256) void k_prep(const float* __restrict__ Fvp,
    float* __restrict__ Fvn, u16* __restrict__ FspAug, u16* __restrict__ Gb){
  __shared__ u16 xa[64*512];
  __shared__ float red[8];
  __shared__ float fvrow[512];
  int b = blockIdx.x, tid = threadIdx.x;
  int lane = tid & 63, wid = tid >> 6, lq = lane & 15, g4 = lane >> 4;
  float x0 = Fvp[b*Cn + tid], x1 = Fvp[b*Cn + tid + 256];
  float2 rr = block_red2(x0*x0 + x1*x1, 0.f, red);
  float inv = 1.f / fmaxf(sqrtf(rr.x), 1e-12f);
  fvrow[tid] = x0*inv; fvrow[tid + 256] = x1*inv;
  Fvn[b*Cn + tid] = x0*inv; Fvn[b*Cn + tid + 256] = x1*inv;
  __syncthreads();
  for (int idx = tid; idx < 64*64; idx += 256){
    int s = idx >> 6, j = idx & 63;
    uint4 v;
    if (s == 56 || s == 57){
      float w[8];
      if (s == 56){
        const float* src = Fvp + b*Cn + j*8;
        #pragma unroll
        for (int k = 0; k < 8; ++k) w[k] = src[k];
      } else {
        #pragma unroll
        for (int k = 0; k < 8; ++k) w[k] = fvrow[j*8 + k];
      }
      v = pack8(w);
      *(uint4*)(FspAug + ((size_t)(b*64 + s))*512 + j*8) = v;
    } else {
      v = *(const uint4*)(FspAug + ((size_t)(b*64 + s))*512 + j*8);
    }
    *(uint4*)(xa + s*512 + ((j ^ (s&7)) << 3)) = v;
  }
  __syncthreads();
  int mt = wid;
  for (int nt = 0; nt < 4; ++nt){
    ffrag acc = {0.f, 0.f, 0.f, 0.f};
    #pragma unroll
    for (int kb = 0; kb < 16; ++kb){
      int j = kb*4 + g4;
      int rowa = mt*16 + lq, rowb = nt*16 + lq;
      bfrag af  = *(const bfrag*)(xa + rowa*512 + ((j ^ (rowa&7)) << 3));
      bfrag bf_ = *(const bfrag*)(xa + rowb*512 + ((j ^ (rowb&7)) << 3));
      acc = __builtin_amdgcn_mfma_f32_16x16x32_bf16(af, bf_, acc, 0, 0, 0);
    }
    #pragma unroll
    for (int r = 0; r < 4; ++r)
      Gb[(size_t)b*4096 + (mt*16 + g4*4 + r)*64 + nt*16 + lq] = f2bf(acc[r]);
  }
}

// ------- K1: scores GEMM -> f16; async staging; grid (Bn, 8) ---------------
__global__ __launch_bounds__(256, 3) void k_scores(const u16* __restrict__ LB,
    const u16* __restrict__ FspAug, u16* __restrict__ Sc){
  __shared__ u16 At[64*256];   // 32768 B
  int b = blockIdx.x, lg = blockIdx.y;
  int tid = threadIdx.x, lane = tid & 63, wid = tid >> 6;
  int lq = lane & 15, g4 = lane >> 4;
  int l32 = lane & 31, rh = lane >> 5;
  bfrag breg[16];
  {
    const u16* fa = FspAug + ((size_t)(b*64 + wid*16 + lq))*512 + g4*8;
    #pragma unroll
    for (int kb = 0; kb < 16; ++kb) breg[kb] = *(const bfrag*)(fa + kb*32);
  }
  for (int chunk = 0; chunk < 4; ++chunk){
    int qi = lg*4 + chunk;
    ffrag acc[4];
    #pragma unroll
    for (int lt = 0; lt < 4; ++lt) acc[lt] = (ffrag){0.f,0.f,0.f,0.f};
    for (int kc = 0; kc < 2; ++kc){
      __syncthreads();   // guard At rewrite
      #pragma unroll
      for (int is = 0; is < 8; ++is){
        int r = (is*4 + wid)*2 + rh;
        const u16* gsrc = LB + (size_t)(qi*64 + r)*512 + kc*256 + ((l32 ^ (r & 7)) << 3);
        u16* ldst = At + ((is*4 + wid) << 9);
        __builtin_amdgcn_global_load_lds((gq_t*)gsrc, (lq_t*)ldst, 16, 0, 0);
      }
      __syncthreads();
      #pragma unroll
      for (int kb = 0; kb < 8; ++kb){
        #pragma unroll
        for (int lt = 0; lt < 4; ++lt){
          int row = lt*16 + lq;
          bfrag af = *(const bfrag*)(At + (row<<8) + (((kb*4+g4) ^ (row&7))<<3));
          acc[lt] = __builtin_amdgcn_mfma_f32_16x16x32_bf16(af, breg[kc*8+kb], acc[lt], 0,0,0);
        }
      }
    }
    #pragma unroll
    for (int lt = 0; lt < 4; ++lt){
      #pragma unroll
      for (int r = 0; r < 4; ++r){
        size_t row = (size_t)b*VQ + qi*64 + lt*16 + g4*4 + r;
        Sc[row*64 + wid*16 + lq] = f2h(acc[lt][r]);
      }
    }
  }
}

// -- K2: row-per-lane softmax + gram epilogue; blocks >= 4096 do proto update
__global__ __launch_bounds__(64) void k_attn4(const void* Fs,
    const u16* __restrict__ Sc, const u16* __restrict__ Gb,
    const float* __restrict__ invFt, const float* __restrict__ invPr,
    const void* gp_, const void* gn_,
    const int* __restrict__ label, const float* __restrict__ Fvn,
    const void* Pr, float* __restrict__ out){
  __shared__ u16 a1t[64*72];
  __shared__ float agab[64], wvb[64];
  __shared__ int lab[128];
  int bid = blockIdx.x;
  int bf = detect_bf(Fs);
  int lane = threadIdx.x;
  if (bid >= 4096){
    int l = bid - 4096;
    lab[lane] = label[lane]; lab[lane + 64] = label[lane + 64];
    __syncthreads();
    float sum[8] = {0.f,0.f,0.f,0.f,0.f,0.f,0.f,0.f};
    int cnt = 0;
    for (int i = 0; i < Bn; ++i){
      if (lab[i] == l){
        cnt++;
        const float4* v = (const float4*)(Fvn + i*Cn + lane*8);
        float4 a = v[0], c = v[1];
        sum[0]+=a.x; sum[1]+=a.y; sum[2]+=a.z; sum[3]+=a.w;
        sum[4]+=c.x; sum[5]+=c.y; sum[6]+=c.z; sum[7]+=c.w;
      }
    }
    int base = l*Cn + lane*8;
    float* dst = out + 3*BL + base;
    if (cnt > 0){
      float sc = 0.01f / fmaxf((float)cnt, 1e-8f);
      #pragma unroll
      for (int j = 0; j < 8; ++j)
        dst[j] = 0.99f*(bf ? ldin<1>(Pr, base+j) : ldin<0>(Pr, base+j)) + sum[j]*sc;
    } else {
      #pragma unroll
      for (int j = 0; j < 8; ++j)
        dst[j] = bf ? ldin<1>(Pr, base+j) : ldin<0>(Pr, base+j);
    }
    return;
  }
  int qi = bid & 31, b = bid >> 5;
  int lq = lane & 15, g4 = lane >> 4;

  u32 w32[32];
  {
    const uint4* rp = (const uint4*)(Sc + ((size_t)b*VQ + qi*64 + lane)*64);
    #pragma unroll
    for (int i = 0; i < 8; ++i){
      uint4 v = rp[i];
      w32[i*4+0] = v.x; w32[i*4+1] = v.y; w32[i*4+2] = v.z; w32[i*4+3] = v.w;
    }
  }
  #define XS(s) h2f((u16)(((s)&1) ? (w32[(s)>>1] >> 16) : (w32[(s)>>1] & 0xffffu)))
  float mx = -1e30f;
  #pragma unroll
  for (int s = 0; s < Sn; ++s) mx = fmaxf(mx, XS(s));
  float raw56 = XS(56), raw57 = XS(57);
  float sm = 0.f, dx = 0.f;
  #pragma unroll
  for (int u = 0; u < 7; ++u){
    u32 pw[4];
    #pragma unroll
    for (int i = 0; i < 4; ++i){
      u32 w2 = 0;
      #pragma unroll
      for (int h = 0; h < 2; ++h){
        int s = u*8 + i*2 + h;
        float x = XS(s);
        float e = (s < Sn) ? __expf(x - mx) : 0.f;
        sm += e; dx += e * x;
        w2 |= ((u32)f2bf(e)) << (16*h);
      }
      pw[i] = w2;
    }
    *(uint4*)(a1t + lane*72 + u*8) = make_uint4(pw[0], pw[1], pw[2], pw[3]);
  }
  #undef XS

  const u16* gbase = Gb + (size_t)b*4096;
  #pragma unroll
  for (int qt = 0; qt < 4; ++qt){
    float pr[4] = {0.f, 0.f, 0.f, 0.f};
    float wvl[4] = {0.f, 0.f, 0.f, 0.f};
    #pragma unroll
    for (int nt = 0; nt < 4; ++nt){
      ffrag acc = {0.f, 0.f, 0.f, 0.f};
      #pragma unroll
      for (int kb2 = 0; kb2 < 2; ++kb2){
        bfrag af;
        if (kb2 == 1 && g4 == 3) af = (bfrag){0,0,0,0,0,0,0,0};
        else af = *(const bfrag*)(a1t + (qt*16 + lq)*72 + (g4 + 4*kb2)*8);
        bfrag bg = *(const bfrag*)(gbase + (nt*16 + lq)*64 + kb2*32 + g4*8);
        acc = __builtin_amdgcn_mfma_f32_16x16x32_bf16(af, bg, acc, 0, 0, 0);
      }
      int sp = nt*16 + lq;
      #pragma unroll
      for (int r = 0; r < 4; ++r){
        int q = qt*16 + g4*4 + r;
        float av = (sp < 56) ? bf2f(a1t[q*72 + sp]) : 0.f;
        pr[r] += av * acc[r];
        if (nt == 3 && lq == 8) wvl[r] = acc[r];
      }
    }
    #pragma unroll
    for (int m = 1; m <= 8; m <<= 1){
      #pragma unroll
      for (int r = 0; r < 4; ++r) pr[r] += __shfl_xor(pr[r], m);
    }
    if (lq == 0){
      #pragma unroll
      for (int r = 0; r < 4; ++r) agab[qt*16 + g4*4 + r] = pr[r];
    }
    if (lq == 8){
      #pragma unroll
      for (int r = 0; r < 4; ++r) wvb[qt*16 + g4*4 + r] = wvl[r];
    }
  }

  int vq = qi*64 + lane;
  int path = vq >> 10, l = vq & 1023;
  if (l < Ln){
    float gp = ld_gamma(gp_, bf), gn = ld_gamma(gn_, bf);
    float fvpSq = bf2f(gbase[56*64 + 56]);
    float inv_sm = 1.f / sm;
    float aGa = agab[lane] * inv_sm * inv_sm;
    float wv  = wvb[lane] * inv_sm;
    float gam = path ? gn : gp;
    float ns  = gam*gam*aGa + 2.f*gam*wv + fvpSq;
    float dt  = gam*(dx*inv_sm) + raw56;
    float invx = (path ? invPr : invFt)[l];
    float lg2 = dt * invx / fmaxf(sqrtf(ns), 1e-12f);
    if (path == 0){
      out[(size_t)b*Ln + l]              = raw57 * invx;
      out[(size_t)BL + (size_t)b*Ln + l] = lg2;
    } else {
      out[(size_t)2*BL + (size_t)b*Ln + l] = lg2;
    }
  }
}

// ---------------------------------------------------------------------------
extern "C" void kernel_launch(void* const* d_in, const int* in_sizes, int n_in,
                              void* d_out, int out_size, void* d_ws, size_t ws_size,
                              hipStream_t stream){
  (void)in_sizes; (void)n_in; (void)out_size; (void)ws_size;
  const void* Fs    = d_in[0];
  const void* Ft    = d_in[1];
  const void* Fv    = d_in[2];
  const int*  label = (const int*)d_in[3];
  const void* gn1g  = d_in[4];
  const void* gn1b  = d_in[5];
  const void* c1w   = d_in[6];
  const void* c1b   = d_in[7];
  const void* gn2g  = d_in[8];
  const void* gn2b  = d_in[9];
  const void* c2w   = d_in[10];
  const void* c2b   = d_in[11];
  const void* ln1g  = d_in[12];
  const void* ln1b  = d_in[13];
  const void* l1w   = d_in[14];
  const void* l1b   = d_in[15];
  const void* ln2g  = d_in[16];
  const void* ln2b  = d_in[17];
  const void* l2w   = d_in[18];
  const void* l2b   = d_in[19];
  const void* gp    = d_in[20];
  const void* gnm   = d_in[21];
  const void* proto = d_in[22];
  float* out = (float*)d_out;
  float* ws  = (float*)d_ws;

  float* m1    = ws + 0;
  float* rs1   = ws + 128;
  float* m2s   = ws + 256;
  float* m2ss  = ws + 384;
  float* invFt = ws + 512;
  float* invPr = ws + 1536;
  u16*   H1t   = (u16*)(ws + 4096);                 // B*49*512 bf16
  float* Fvp   = ws + 4096 + (size_t)Bn*Sn*Cn/2;    // B*C f32
  float* Fvn   = Fvp + Bn*Cn;
  u16*   FspAug= (u16*)(Fvn + Bn*Cn);               // B*64*512 bf16
  u16*   FtB   = FspAug + (size_t)Bn*64*512;        // 1024*512 bf16 (PrB follows)
  u16*   PrB   = FtB + (size_t)1024*512;
  u16*   Gb    = PrB + (size_t)1024*512;            // B*64*64 bf16
  u16*   W1b   = Gb + (size_t)Bn*4096;              // 512*512 bf16 x4
  u16*   W2b   = W1b + (size_t)512*512;
  u16*   W1vb  = W2b + (size_t)512*512;
  u16*   W2vb  = W1vb + (size_t)512*512;
  u16*   Hb    = W2vb + (size_t)512*512;            // 128*512 bf16
  u16*   Fsb   = Hb + (size_t)Bn*Cn;                // B*49*512 bf16
  float* Kv1a  = (float*)(Fsb + (size_t)Bn*Sn*Cn);  // 4 x 512 f32
  float* Kv1b  = Kv1a + 512;
  float* Kv2a  = Kv1b + 512;
  float* Kv2b  = Kv2a + 512;
  u16*   Sc    = (u16*)(Kv2b + 512);                // B*2048*64 f16 (33.5MB)

  k_gn1wk<<<1920, 256, 0, stream>>>(Fs, c1w, c2w, l1w, l2w, gn1g, gn2g,
                                    gn1b, gn2b, c1b, c2b,
                                    W1b, W2b, W1vb, W2vb, Kv1a, Kv1b, Kv2a, Kv2b,
                                    Ft, proto, invFt, invPr, FtB, PrB,
                                    m1, rs1, Fsb, m2s, m2ss);
  k_c1vg1<<<288, 512, 0, stream>>>(Fs, Fsb, W1b, Kv1a, Kv1b, m1, rs1, H1t, m2s, m2ss,
                                   Fv, ln1g, ln1b, W1vb, l1b, Hb);
  k_c2vg2<<<288, 512, 0, stream>>>(Fs, H1t, W2b, Kv2a, Kv2b, m2s, m2ss, FspAug,
                                   Hb, ln2g, ln2b, W2vb, l2b, Fvp);
  k_prep<<<Bn, 256, 0, stream>>>(Fvp, Fvn, FspAug, Gb);
  k_scores<<<dim3(Bn, 8), 256, 0, stream>>>(FtB, FspAug, Sc);
  k_attn4<<<4096 + Ln, 64, 0, stream>>>(Fs, Sc, Gb, invFt, invPr, gp, gnm,
                                        label, Fvn, proto, out);
}